// Round 11
// baseline (560.758 us; speedup 1.0000x reference)
//
#include <hip/hip_runtime.h>
#include <hip/hip_bf16.h>
#include <stdint.h>

// DH-SNN forward: two-phase optimistic execution, v3 decomposition.
// Phase 1 (free-run): WG = 32 rows (rtile=wg&3) x 64 cols (ctile=wg>>2).
//   - Wave (cg,p): 32 cols (2 tiles) x k-half (11 chunks): B = 22 frags = 88 VGPR -> RESIDENT.
//   - A (32 rows, 45KB/step) triple-buffered; counted vmcnt drain PRE-barrier (all-wave safe).
//   - k-split partial-C combine: symmetric row-tile exchange (2 b128 w + 2 b128 r per wave).
//   - Update in MFMA C-layout (lane = column): quad-lane mov_dpp sum for branch l_in;
//     no curL transpose. Zero-spike speculation; memmax>VTH = violation.
//   - Readout recurrence is input-independent under zero spikes -> hoisted out of the loop.
// Verdict: 256 single-hop flags; clean half -> write out; dirty half -> phase 2 (verbatim R7).

typedef short short8 __attribute__((ext_vector_type(8)));
typedef float f32x4 __attribute__((ext_vector_type(4)));

#define T_STEPS 250
#define BATCH   128
#define HID     1024
#define NCOL    4096
#define IND     700
#define ISZ     1724
#define KPAD    704
#define OUTD    20
#define NWG     256
#define WGT     256
#define UPB     5632      // 16B units per (t,half64) A block

// ws layout (bytes)
#define O_P1F   0                // u64[256] phase-1 flags (idx = rtile*64+ctile)
#define O_SUM   2048             // u64[2 parity][2 half][128 wg]
#define O_CHK   6144             // u64[2][2][128][16]
#define O_WST   71680            // f32 [1024][4096]
#define O_WXH   16848896         // bf16 [4096][704]
#define O_XH    22616064         // bf16 [250][2][5632][8] swizzled

// smem arena (phase-1/phase-2 alias deliberately; phase 2 restages everything)
#define SM_BP    0               // phase2: Wx^T panel 45568
#define SM_A2    45568           // phase2: ApreB 90112
#define SM_CURL2 135680          // phase2: C exchange 9216
#define SM_MTB   144896          // phase2: masks 8704
#define SM_TOTAL 153600
// phase1 overlay: Abuf = smem+0 (3 x 45056 = 135168); preg = smem+135168 (16384)

#define AGENT __HIP_MEMORY_SCOPE_AGENT

__device__ __forceinline__ float sigmoidf(float x) { return 1.0f / (1.0f + expf(-x)); }

__device__ __forceinline__ unsigned ldsLd(const unsigned* p) {
    return __hip_atomic_load(p, __ATOMIC_ACQUIRE, __HIP_MEMORY_SCOPE_WORKGROUP);
}
__device__ __forceinline__ void ldsSt(unsigned* p, unsigned v) {
    __hip_atomic_store(p, v, __ATOMIC_RELEASE, __HIP_MEMORY_SCOPE_WORKGROUP);
}

__device__ __forceinline__ void dma16(const void* g, void* l) {
    __builtin_amdgcn_global_load_lds(
        (const __attribute__((address_space(1))) unsigned int*)g,
        (__attribute__((address_space(3))) unsigned int*)l, 16, 0, 0);
}

// quad-lane sum (lanes xor 1, xor 2) via DPP quad_perm — pure VALU, no LDS pipe
__device__ __forceinline__ float qsum4(float v) {
    union { float f; int i; } a, b;
    a.f = v; b.i = __builtin_amdgcn_mov_dpp(a.i, 0xB1, 0xF, 0xF, true); v += b.f;  // xor 1
    a.f = v; b.i = __builtin_amdgcn_mov_dpp(a.i, 0x4E, 0xF, 0xF, true); v += b.f;  // xor 2
    return v;
}

// phase-1: each wave issues its 11 of the 44 1KB-units of a 32-row A slice
__device__ __forceinline__ void issueA2(const __hip_bfloat16* Xh, int t, int halfI,
                                        size_t subOff, uint8_t* dbuf, int wid, int lane) {
    const char* g = (const char*)Xh + ((size_t)(t * 2 + halfI)) * UPB * 16 + subOff;
    #pragma unroll
    for (int i = 0; i < 11; ++i) {
        int j = wid * 11 + i;
        dma16(g + (size_t)j * 1024 + (size_t)lane * 16, dbuf + j * 1024);
    }
}

// x -> Xh, pre-swizzled: unit q of block (t,half64) holds (row=q/88, k=((q%88)^(row&7))*8+e).
__global__ void prep_x(const float* __restrict__ x, __hip_bfloat16* __restrict__ Xh) {
    const int total = T_STEPS * 2 * UPB;
    for (int unit = blockIdx.x * blockDim.x + threadIdx.x; unit < total;
         unit += gridDim.x * blockDim.x) {
        int q   = unit % UPB;
        int blk = unit / UPB;
        int half = blk & 1, t = blk >> 1;
        int row = q / 88, m = q % 88;
        int k8  = m ^ (row & 7);
        int b   = half * 64 + row;
        const float* xp = x + ((long)b * T_STEPS + t) * IND + k8 * 8;
        short8 o;
        #pragma unroll
        for (int e = 0; e < 8; ++e) {
            int k = k8 * 8 + e;
            float v = (k < IND) ? xp[e] : 0.0f;
            union { __hip_bfloat16 h; short s; } u;
            u.h = __float2bfloat16(v);
            o[e] = u.s;
        }
        *(short8*)(Xh + (size_t)unit * 8) = o;
    }
}

__global__ void prep_w(const float* __restrict__ W, __hip_bfloat16* __restrict__ Wxh,
                       uint64_t* __restrict__ p1f, uint64_t* __restrict__ sums,
                       uint64_t* __restrict__ chunks) {
    if (blockIdx.x == 0) {       // zero exchange area every launch (replay + 0xAA poison)
        for (int i = threadIdx.x; i < 256; i += blockDim.x)
            __hip_atomic_store(&p1f[i], 0ull, __ATOMIC_RELAXED, AGENT);
        for (int i = threadIdx.x; i < 2 * 2 * 128; i += blockDim.x)
            __hip_atomic_store(&sums[i], 0ull, __ATOMIC_RELAXED, AGENT);
        for (int i = threadIdx.x; i < 2 * 2 * 128 * 16; i += blockDim.x)
            __hip_atomic_store(&chunks[i], 0ull, __ATOMIC_RELAXED, AGENT);
    }
    const int total = NCOL * KPAD;
    for (int idx = blockIdx.x * blockDim.x + threadIdx.x; idx < total; idx += gridDim.x * blockDim.x) {
        int k = idx % KPAD;
        int n = idx / KPAD;
        float v = (k < IND) ? W[(long)n * ISZ + k] : 0.0f;
        Wxh[idx] = __float2bfloat16(v);
    }
}

// Wst[h][n] = W[n][700+h]
__global__ __launch_bounds__(256) void prep_t(const float* __restrict__ W, float* __restrict__ Wst) {
    __shared__ float tile[32][33];
    const int h0 = blockIdx.x * 32, n0 = blockIdx.y * 32;
    const int tx = threadIdx.x, ty = threadIdx.y;
    #pragma unroll
    for (int j = 0; j < 32; j += 8)
        tile[ty + j][tx] = W[(long)(n0 + ty + j) * ISZ + IND + h0 + tx];
    __syncthreads();
    #pragma unroll
    for (int j = 0; j < 32; j += 8)
        Wst[(long)(h0 + ty + j) * NCOL + n0 + tx] = tile[tx][ty + j];
}

__global__ __launch_bounds__(256, 1) void snn_scan(
    const __hip_bfloat16* __restrict__ Xh, const __hip_bfloat16* __restrict__ Wxh,
    const float* __restrict__ Wst, uint64_t* __restrict__ p1f, uint64_t* __restrict__ sums,
    uint64_t* __restrict__ chunks,
    const float* __restrict__ bvec, const float* __restrict__ tau_m, const float* __restrict__ tau_n,
    const float* __restrict__ Wr, const float* __restrict__ brv, const float* __restrict__ tau_r,
    const float* __restrict__ mem0, float* __restrict__ out)
{
    __shared__ __align__(16) char smem[SM_TOTAL];
    __shared__ uint32_t stageW[16];
    __shared__ uint64_t roSnap[16];
    __shared__ unsigned fPollDone[2], fStgw[2], fCorr[2];
    __shared__ unsigned fRoSnap, anySpkF, dirtyH[2];

    __hip_bfloat16* Bp    = (__hip_bfloat16*)(smem + SM_BP);
    uint8_t*        Abuf  = (uint8_t*)smem;                 // phase1: 3 x 45056
    float*          preg  = (float*)(smem + 135168);        // phase1: 2 parity x 8 slots x 1024B
    uint8_t*        Apre2 = (uint8_t*)(smem + SM_A2);
    float*          curL2 = (float*)(smem + SM_CURL2);
    uint8_t*        mTb   = (uint8_t*)(smem + SM_MTB);

    const int wg    = blockIdx.x;
    const int rtile = wg & 3;         // rows [rtile*32, +32)  (XCD-constant under round-robin)
    const int ctile = wg >> 2;        // cols [ctile*64, +64)
    const int tid   = threadIdx.x;
    const int lane  = tid & 63, wid = tid >> 6;
    const int colA  = lane & 15, kb8 = (lane >> 4) * 8;
    const int cg    = wid >> 1;       // col-group: cols [cg*32, +32) within WG
    const int p     = wid & 1;        // k-half: chunks [11p, 11p+11); owns row-tile p

    if (tid < 2) { fPollDone[tid] = 0; fStgw[tid] = 0; fCorr[tid] = 0; dirtyH[tid] = 0; }
    if (tid == 0) { fRoSnap = 0; anySpkF = 0; }

    // readout consts (o = lane) — shared by both phases
    float r_alpha = 0.f, r_bias = 0.f;
    const float* WrRow = Wr;
    if (wid == 0 && lane < 32) {
        int o = (lane < OUTD) ? lane : 0;
        r_alpha = sigmoidf(tau_r[o]);
        r_bias  = brv[o];
        WrRow   = Wr + o * HID;
    }
    const int roB1 = (ctile < 32) ? rtile * 32 + ctile : -1;

    // ---------------- phase-1 per-lane state (C-layout): 2 cols x 4 rows ----------------
    const int colG0 = ctile * 64 + cg * 32 + colA;        // tile i=0
    const int colG1 = colG0 + 16;                          // tile i=1
    const int rowB  = rtile * 32 + p * 16 + (lane >> 4) * 4;   // own row-tile = p
    float bt_[2], omb_[2], bias_[2], al_[2], oma_[2], dn[2][4], mem[2][4];
    {
        const int cG[2] = {colG0, colG1};
        #pragma unroll
        for (int i = 0; i < 2; ++i) {
            bt_[i]   = sigmoidf(tau_n[cG[i]]);
            omb_[i]  = 1.0f - bt_[i];
            bias_[i] = bvec[cG[i]];
            al_[i]   = sigmoidf(tau_m[cG[i] >> 2]);
            oma_[i]  = 1.0f - al_[i];
            #pragma unroll
            for (int j = 0; j < 4; ++j) {
                dn[i][j]  = 0.0f;
                mem[i][j] = mem0[(rowB + j) * HID + (cG[i] >> 2)];
            }
        }
    }

    // ---------------- B panel -> registers: 22 frags = 88 VGPR (resident) ----------------
    short8 Breg[22];
    #pragma unroll
    for (int j = 0; j < 11; ++j) {
        Breg[2 * j]     = *(const short8*)(Wxh + (long)colG0 * KPAD + (11 * p + j) * 32 + kb8);
        Breg[2 * j + 1] = *(const short8*)(Wxh + (long)colG1 * KPAD + (11 * p + j) * 32 + kb8);
    }
    asm volatile("s_waitcnt vmcnt(0)" ::: "memory");
    __builtin_amdgcn_sched_barrier(0);
    #pragma unroll
    for (int i = 0; i < 22; ++i) asm volatile("" : "+v"(Breg[i]));

    // ---------------- A pipeline prologue ----------------
    const int    halfI  = rtile >> 1;
    const size_t subOff = (size_t)(rtile & 1) * 45056;
    issueA2(Xh, 0, halfI, subOff, Abuf, wid, lane);
    issueA2(Xh, 1, halfI, subOff, Abuf + 45056, wid, lane);
    asm volatile("s_waitcnt vmcnt(11)" ::: "memory");   // own buf0 units done
    __syncthreads();                                     // all waves' buf0 done

    // ================= PHASE 1: optimistic free-run =================
    float memmax = -1e30f;
    for (int t = 0; t < T_STEPS; ++t) {
        // 1. issue DMA[t+2]
        if (t + 2 < T_STEPS)
            issueA2(Xh, t + 2, halfI, subOff, Abuf + ((t + 2) % 3) * 45056, wid, lane);

        // 2. MFMA: 2 col-tiles x 2 row-tiles x 11 k-chunks, B from regs
        f32x4 aA0 = {0,0,0,0}, aB0 = {0,0,0,0}, aA1 = {0,0,0,0}, aB1 = {0,0,0,0};
        const uint8_t* Ab = Abuf + (t % 3) * 45056;
        #pragma unroll
        for (int j = 0; j < 11; ++j) {
            int c = 11 * p + j;
            int u = (c * 4 + (lane >> 4)) ^ (lane & 7);
            const uint8_t* base = Ab + colA * 1408 + u * 16;
            short8 a0 = *(const short8*)(base);            // rows 0-15
            short8 a1 = *(const short8*)(base + 22528);    // rows 16-31
            aA0 = __builtin_amdgcn_mfma_f32_16x16x32_bf16(a0, Breg[2 * j],     aA0, 0, 0, 0);
            aB0 = __builtin_amdgcn_mfma_f32_16x16x32_bf16(a0, Breg[2 * j + 1], aB0, 0, 0, 0);
            aA1 = __builtin_amdgcn_mfma_f32_16x16x32_bf16(a1, Breg[2 * j],     aA1, 0, 0, 0);
            aB1 = __builtin_amdgcn_mfma_f32_16x16x32_bf16(a1, Breg[2 * j + 1], aB1, 0, 0, 0);
        }

        // 3. symmetric partial exchange: send row-tile (1-p), keep row-tile p
        f32x4 own0, own1, snd0, snd1;
        if (p == 0) { own0 = aA0; own1 = aB0; snd0 = aA1; snd1 = aB1; }
        else        { own0 = aA1; own1 = aB1; snd0 = aA0; snd1 = aB0; }
        {
            float* w0 = preg + (t & 1) * 2048 + ((cg * 2 + (1 - p)) * 2 + 0) * 256 + lane * 4;
            float* w1 = preg + (t & 1) * 2048 + ((cg * 2 + (1 - p)) * 2 + 1) * 256 + lane * 4;
            *(f32x4*)w0 = snd0;
            *(f32x4*)w1 = snd1;
        }
        if (t + 2 < T_STEPS) asm volatile("s_waitcnt vmcnt(11) lgkmcnt(0)" ::: "memory");
        else                 asm volatile("s_waitcnt vmcnt(0) lgkmcnt(0)" ::: "memory");
        __builtin_amdgcn_sched_barrier(0);
        __builtin_amdgcn_s_barrier();

        // 4. combine + zero-spike update in C-layout (lane = column; quad-dpp branch sum)
        {
            const float* r0 = preg + (t & 1) * 2048 + ((cg * 2 + p) * 2 + 0) * 256 + lane * 4;
            const float* r1 = preg + (t & 1) * 2048 + ((cg * 2 + p) * 2 + 1) * 256 + lane * 4;
            f32x4 cs0 = own0 + *(const f32x4*)r0;
            f32x4 cs1 = own1 + *(const f32x4*)r1;
            #pragma unroll
            for (int j = 0; j < 4; ++j) {
                float d0 = bt_[0] * dn[0][j] + omb_[0] * (cs0[j] + bias_[0]);
                float d1 = bt_[1] * dn[1][j] + omb_[1] * (cs1[j] + bias_[1]);
                dn[0][j] = d0; dn[1][j] = d1;
                float l0 = qsum4(d0), l1 = qsum4(d1);
                float m0 = al_[0] * mem[0][j] + oma_[0] * l0;   // VTH=1; spk==0 assumed
                float m1 = al_[1] * mem[1][j] + oma_[1] * l1;
                mem[0][j] = m0; mem[1][j] = m1;
                memmax = fmaxf(memmax, fmaxf(m0, m1));
            }
        }
    }

    // ---------------- verdict ----------------
    if (__any(memmax > 1.0f) && lane == 0) anySpkF = 1u;
    __syncthreads();
    if (tid == 0)
        __hip_atomic_store(p1f + rtile * 64 + ctile,
                           (1ull << 32) | (uint64_t)anySpkF, __ATOMIC_RELAXED, AGENT);
    {
        const uint64_t* fp = p1f + tid;   // 256 threads <-> 256 flags
        uint64_t v;
        for (;;) {
            v = __hip_atomic_load(fp, __ATOMIC_RELAXED, AGENT);
            if ((unsigned)(v >> 32) == 1u) break;
            __builtin_amdgcn_s_sleep(1);
        }
        if ((unsigned)v != 0u) dirtyH[tid >> 7] = 1u;   // idx<128 <=> rows 0..63
    }
    __syncthreads();

    // clean half: hoisted readout (input-independent under zero spikes) + write out
    if (!dirtyH[rtile >> 1] && wid == 0 && roB1 >= 0 && lane < 32) {
        float rr = 0.f, racc = 0.f;
        for (int t = 0; t < T_STEPS; ++t) {
            rr = r_alpha * rr + (1.0f - r_alpha) * r_bias;   // rsum = 0
            float vmax = (lane < OUTD) ? rr : -__builtin_inff();
            #pragma unroll
            for (int d = 16; d > 0; d >>= 1) vmax = fmaxf(vmax, __shfl_xor(vmax, d, 32));
            float e = (lane < OUTD) ? expf(rr - vmax) : 0.f;
            float ss = e;
            #pragma unroll
            for (int d = 16; d > 0; d >>= 1) ss += __shfl_xor(ss, d, 32);
            if (t >= 1) racc += e / ss;   // WARMUP=0
        }
        if (lane < OUTD) out[roB1 * OUTD + lane] = racc;
    }
    if (!dirtyH[wg >> 7]) return;

    // ================= PHASE 2: synchronous fallback (R7 algorithm, tags +1) ============
    float r_rmem = 0.f, r_acc = 0.f;
    const int w2    = wg & 127;
    const int bhalf = wg >> 7;
    const int bbase = bhalf * 64;
    const int c0    = w2 * 32;
    const int i0    = w2 * 8;
    const int roB2  = (wg < 64) ? wg : ((wg >= 128 && wg < 192) ? wg - 64 : -1);

    // deferred staging: Bp (vectorized) + mTb zero
    for (int idx = tid; idx < 32 * 88; idx += WGT) {
        int col = idx / 88, m = idx % 88;
        *(short8*)(Bp + col * 712 + m * 8) = *(const short8*)(Wxh + (long)(c0 + col) * KPAD + m * 8);
    }
    for (int idx = tid; idx < 64 * 136 / 4; idx += WGT)
        ((uint32_t*)mTb)[idx] = 0u;

    const int mwid = wid - 2;
    const int st   = tid - 128;
    const int r2   = st >> 1;
    const int half = st & 1;
    float dn2[16], bt2[16], omb2[16], bias2[16], alph2[4], oma2[4], mem2[4], spk2[4];
    if (wid >= 2) {
        const int b2 = bbase + r2;
        #pragma unroll
        for (int n = 0; n < 4; ++n) {
            int i = i0 + half * 4 + n;
            alph2[n] = sigmoidf(tau_m[i]);
            oma2[n]  = 1.0f - alph2[n];
            mem2[n]  = mem0[b2 * HID + i];
            spk2[n]  = 0.0f;
            #pragma unroll
            for (int j = 0; j < 4; ++j) {
                int idx = n * 4 + j;
                bt2[idx]   = sigmoidf(tau_n[i * 4 + j]);
                omb2[idx]  = 1.0f - bt2[idx];
                bias2[idx] = bvec[i * 4 + j];
                dn2[idx]   = 0.0f;
            }
        }
    }
    const int trRow = mwid * 32;
    const int rb2   = trRow + (lane & 15);
    const int sw2   = rb2 & 7;
    uint8_t* dst2   = Apre2 + mwid * 45056;

    if (wid >= 2) {
        const char* gsrc = (const char*)Xh + ((size_t)bhalf * UPB) * 16 + (size_t)mwid * 45056;
        #pragma unroll
        for (int i = 0; i < 44; ++i)
            dma16(gsrc + i * 1024 + lane * 16, dst2 + i * 1024);
    }
    asm volatile("s_waitcnt vmcnt(0)" ::: "memory");
    __syncthreads();

    if (wid < 2) {
        // ---- poll waves ----
        const int plane = tid;
        for (int k = 1; k <= T_STEPS; ++k) {
            const size_t base = ((size_t)((k - 1) & 1) * 2 + bhalf) * 128 + plane;
            const unsigned want = (unsigned)(k + 1);
            uint64_t v;
            for (;;) {
                v = __hip_atomic_load(sums + base, __ATOMIC_RELAXED, AGENT);
                if ((unsigned)(v >> 32) == want) break;
                __builtin_amdgcn_s_sleep(1);
            }
            unsigned mysum = (unsigned)v;
            if (mysum) {
                if (wid == 1)
                    while (ldsLd(&fRoSnap) < (unsigned)(k - 1)) {}
                const uint64_t* rec = chunks + base * 16;
                uint8_t* col = mTb + plane;
                unsigned pend = mysum;
                while (pend) {
                    int c = __builtin_ctz(pend);
                    uint64_t cv = __hip_atomic_load(rec + c, __ATOMIC_RELAXED, AGENT);
                    if ((unsigned)(cv >> 32) == want) {
                        pend &= pend - 1;
                        unsigned pay = (unsigned)cv;
                        col[(4 * c + 0) * 136] = (uint8_t)(pay);
                        col[(4 * c + 1) * 136] = (uint8_t)(pay >> 8);
                        col[(4 * c + 2) * 136] = (uint8_t)(pay >> 16);
                        col[(4 * c + 3) * 136] = (uint8_t)(pay >> 24);
                    } else {
                        __builtin_amdgcn_s_sleep(1);
                    }
                }
            }
            const bool anyW = __any(mysum != 0u);
            if (lane == 0)
                ldsSt(&fPollDone[wid], ((unsigned)k << 1) | (anyW ? 1u : 0u));

            if (wid == 0) {
                while ((ldsLd(&fPollDone[1]) >> 1) < (unsigned)k) {}
                if (roB2 >= 0 && lane < 16)
                    roSnap[lane] = ((const uint64_t*)(mTb + (roB2 & 63) * 136))[lane];
                asm volatile("s_waitcnt lgkmcnt(0)" ::: "memory");
                if (lane == 0) ldsSt(&fRoSnap, (unsigned)k);
                if (roB2 >= 0 && lane < 32) {
                    float rsum = 0.f;
                    #pragma unroll 4
                    for (int q = 0; q < 16; ++q) {
                        uint64_t mword = roSnap[q];
                        while (mword) {
                            int h = (q << 6) + __builtin_ctzll(mword);
                            mword &= mword - 1;
                            rsum += WrRow[h];
                        }
                    }
                    r_rmem = r_alpha * r_rmem + (1.0f - r_alpha) * (rsum + r_bias);
                    float vmax = (lane < OUTD) ? r_rmem : -__builtin_inff();
                    #pragma unroll
                    for (int d = 16; d > 0; d >>= 1) vmax = fmaxf(vmax, __shfl_xor(vmax, d, 32));
                    float e = (lane < OUTD) ? expf(r_rmem - vmax) : 0.f;
                    float ssum = e;
                    #pragma unroll
                    for (int d = 16; d > 0; d >>= 1) ssum += __shfl_xor(ssum, d, 32);
                    if (k >= 2) r_acc += e / ssum;
                }
            }
        }
        if (wid == 0 && roB2 >= 0 && lane < OUTD) out[roB2 * OUTD + lane] = r_acc;
    } else {
        // ---- compute waves ----
        const float* clp = curL2 + r2 * 36 + half * 16;
        for (int t = 0; t < T_STEPS; ++t) {
            f32x4 a00 = {0,0,0,0}, a01 = {0,0,0,0}, a10 = {0,0,0,0}, a11 = {0,0,0,0};
            #pragma unroll
            for (int k0 = 0; k0 < KPAD; k0 += 32) {
                int k8 = (k0 >> 3) + (lane >> 4);
                short8 f0 = *(const short8*)&Apre2[(((rb2)      * 88 + (k8 ^ sw2)) << 4)];
                short8 f1 = *(const short8*)&Apre2[(((rb2 + 16) * 88 + (k8 ^ sw2)) << 4)];
                short8 b0 = *(const short8*)(&Bp[(colA) * 712 + k0 + kb8]);
                short8 b1 = *(const short8*)(&Bp[(16 + colA) * 712 + k0 + kb8]);
                a00 = __builtin_amdgcn_mfma_f32_16x16x32_bf16(f0, b0, a00, 0, 0, 0);
                a01 = __builtin_amdgcn_mfma_f32_16x16x32_bf16(f0, b1, a01, 0, 0, 0);
                a10 = __builtin_amdgcn_mfma_f32_16x16x32_bf16(f1, b0, a10, 0, 0, 0);
                a11 = __builtin_amdgcn_mfma_f32_16x16x32_bf16(f1, b1, a11, 0, 0, 0);
            }
            asm volatile("s_waitcnt lgkmcnt(0)" ::: "memory");
            __builtin_amdgcn_sched_barrier(0);
            if (t + 1 < T_STEPS) {
                const char* gsrc = (const char*)Xh
                    + (((size_t)(t + 1) * 2 + bhalf) * UPB) * 16 + (size_t)mwid * 45056;
                #pragma unroll
                for (int i = 0; i < 44; ++i)
                    dma16(gsrc + i * 1024 + lane * 16, dst2 + i * 1024);
            }
            {
                const int crow0 = trRow + ((lane >> 4) << 2);
                #pragma unroll
                for (int j = 0; j < 4; ++j) {
                    curL2[(crow0 + j) * 36 + colA]           = a00[j];
                    curL2[(crow0 + j) * 36 + 16 + colA]      = a01[j];
                    curL2[(crow0 + 16 + j) * 36 + colA]      = a10[j];
                    curL2[(crow0 + 16 + j) * 36 + 16 + colA] = a11[j];
                }
            }
            asm volatile("s_waitcnt lgkmcnt(0)" ::: "memory");
            __builtin_amdgcn_sched_barrier(0);

            f32x4 cv0 = *(const f32x4*)(clp + 0);
            f32x4 cv1 = *(const f32x4*)(clp + 4);
            f32x4 cv2 = *(const f32x4*)(clp + 8);
            f32x4 cv3 = *(const f32x4*)(clp + 12);
            float cl[16];
            #pragma unroll
            for (int e = 0; e < 4; ++e) {
                cl[e] = cv0[e]; cl[4 + e] = cv1[e]; cl[8 + e] = cv2[e]; cl[12 + e] = cv3[e];
            }
            float memS[4], spkS[4];
            #pragma unroll
            for (int n = 0; n < 4; ++n) {
                float lin = 0.f;
                #pragma unroll
                for (int j = 0; j < 4; ++j) {
                    int idx = n * 4 + j;
                    dn2[idx] = bt2[idx] * dn2[idx] + omb2[idx] * (cl[idx] + bias2[idx]);
                    lin += dn2[idx];
                }
                memS[n] = alph2[n] * mem2[n] + oma2[n] * lin - spk2[n];
                spkS[n] = (memS[n] > 1.0f) ? 1.0f : 0.0f;
            }
            unsigned nib = 0;
            #pragma unroll
            for (int n = 0; n < 4; ++n) nib |= (spkS[n] != 0.f ? 1u : 0u) << (half * 4 + n);
            nib |= (unsigned)__shfl_xor((int)nib, 1);
            if (half == 0) ((uint8_t*)stageW)[r2] = (uint8_t)nib;
            if (lane == 0) ldsSt(&fStgw[mwid], (unsigned)(t + 1));

            bool anySpk = false;
            if (t > 0) {
                unsigned p0, p1;
                do { p0 = ldsLd(&fPollDone[0]); } while ((p0 >> 1) < (unsigned)t);
                do { p1 = ldsLd(&fPollDone[1]); } while ((p1 >> 1) < (unsigned)t);
                anySpk = ((p0 | p1) & 1u) != 0u;
            }
            if (anySpk) {
                float recv[16];
                #pragma unroll
                for (int e = 0; e < 16; ++e) recv[e] = 0.f;
                const float* Wb = Wst + c0 + half * 16;
                const uint64_t* mrow = (const uint64_t*)(mTb + r2 * 136);
                for (int q = 0; q < 16; ++q) {
                    uint64_t mword = mrow[q];
                    while (mword) {
                        int h = (q << 6) + __builtin_ctzll(mword);
                        mword &= mword - 1;
                        const f32x4* wv = (const f32x4*)(Wb + (long)h * NCOL);
                        f32x4 w0 = wv[0], w1 = wv[1], w2v = wv[2], w3 = wv[3];
                        #pragma unroll
                        for (int e = 0; e < 4; ++e) {
                            recv[e] += w0[e]; recv[4 + e] += w1[e];
                            recv[8 + e] += w2v[e]; recv[12 + e] += w3[e];
                        }
                    }
                }
                #pragma unroll
                for (int n = 0; n < 4; ++n) {
                    float cs = 0.f;
                    #pragma unroll
                    for (int j = 0; j < 4; ++j) {
                        int idx = n * 4 + j;
                        float ad = omb2[idx] * recv[idx];
                        dn2[idx] += ad; cs += ad;
                    }
                    memS[n] += oma2[n] * cs;
                    spkS[n] = (memS[n] > 1.0f) ? 1.0f : 0.0f;
                }
                unsigned nib2 = 0;
                #pragma unroll
                for (int n = 0; n < 4; ++n) nib2 |= (spkS[n] != 0.f ? 1u : 0u) << (half * 4 + n);
                nib2 |= (unsigned)__shfl_xor((int)nib2, 1);
                if (half == 0) ((uint8_t*)stageW)[r2] = (uint8_t)nib2;
                if (roB2 >= 0) while (ldsLd(&fRoSnap) < (unsigned)t) {}
                uint64_t* mz = (uint64_t*)(mTb + r2 * 136) + half * 8;
                #pragma unroll
                for (int e = 0; e < 8; ++e) mz[e] = 0;
                if (lane == 0) ldsSt(&fCorr[mwid], (unsigned)(t + 1));
            }
            #pragma unroll
            for (int n = 0; n < 4; ++n) { mem2[n] = memS[n]; spk2[n] = spkS[n]; }

            if (mwid == 0) {
                while (ldsLd(&fStgw[1]) < (unsigned)(t + 1)) {}
                if (anySpk) while (ldsLd(&fCorr[1]) < (unsigned)(t + 1)) {}
                unsigned pay = (lane < 16) ? stageW[lane] : 0u;
                const size_t pbase = ((size_t)(t & 1) * 2 + bhalf) * 128 + w2;
                if (lane < 16 && pay)
                    __hip_atomic_store(chunks + pbase * 16 + lane,
                                       ((uint64_t)(unsigned)(t + 2) << 32) | (uint64_t)pay,
                                       __ATOMIC_RELAXED, AGENT);
                uint64_t bal = __ballot(pay != 0u);
                if (lane == 0)
                    __hip_atomic_store(sums + pbase,
                                       ((uint64_t)(unsigned)(t + 2) << 32) | (uint64_t)(bal & 0xFFFFull),
                                       __ATOMIC_RELAXED, AGENT);
            }
            asm volatile("s_waitcnt vmcnt(0)" ::: "memory");
        }
    }
}

extern "C" void kernel_launch(void* const* d_in, const int* in_sizes, int n_in,
                              void* d_out, int out_size, void* d_ws, size_t ws_size,
                              hipStream_t stream) {
    (void)in_sizes; (void)n_in; (void)out_size; (void)ws_size;
    const float* x     = (const float*)d_in[0];
    const float* W     = (const float*)d_in[1];
    const float* bv    = (const float*)d_in[2];
    const float* tau_m = (const float*)d_in[3];
    const float* tau_n = (const float*)d_in[4];
    const float* Wr    = (const float*)d_in[5];
    const float* br    = (const float*)d_in[6];
    const float* tau_r = (const float*)d_in[7];
    const float* mem0  = (const float*)d_in[8];

    char* ws = (char*)d_ws;
    uint64_t*        p1flag = (uint64_t*)(ws + O_P1F);
    uint64_t*        sums   = (uint64_t*)(ws + O_SUM);
    uint64_t*        chunks = (uint64_t*)(ws + O_CHK);
    float*           Wst    = (float*)(ws + O_WST);
    __hip_bfloat16*  Wxh    = (__hip_bfloat16*)(ws + O_WXH);
    __hip_bfloat16*  Xh     = (__hip_bfloat16*)(ws + O_XH);

    prep_x<<<2048, 256, 0, stream>>>(x, Xh);
    prep_w<<<2048, 256, 0, stream>>>(W, Wxh, p1flag, sums, chunks);
    dim3 g3(32, 128), b3(32, 8);
    prep_t<<<g3, b3, 0, stream>>>(W, Wst);
    snn_scan<<<NWG, WGT, 0, stream>>>(Xh, Wxh, Wst, p1flag, sums, chunks,
                                      bv, tau_m, tau_n, Wr, br, tau_r, mem0, (float*)d_out);
}

// Round 12
// 560.669 us; speedup vs baseline: 1.0002x; 1.0002x over previous
//
#include <hip/hip_runtime.h>
#include <hip/hip_bf16.h>
#include <stdint.h>

// DH-SNN forward: two-phase optimistic execution, v3 decomposition.
// Phase 1 (free-run): WG = 32 rows (rtile=wg&3) x 64 cols (ctile=wg>>2).
//   - Wave (cg,p): 32 cols (2 tiles) x k-half (11 chunks): B = 22 frags = 88 VGPR.
//   - amdgpu_waves_per_eu(1,1): allocator budget = 512 VGPR -> B genuinely RESIDENT
//     (R9-R11 failure mode: allocator capped at 132 VGPR and re-loaded B from L2 every
//      step -> ~5.8MB/XCD/step = the 2us/step L2 floor).
//   - A (32 rows, 45KB/step) triple-buffered in LDS; counted vmcnt drain PRE-barrier.
//   - k-split partial-C combine: symmetric row-tile exchange (2 b128 w + 2 b128 r per wave).
//   - Update in MFMA C-layout (lane = column): quad-lane mov_dpp sum for branch l_in.
//     Zero-spike speculation; memmax>VTH = violation. Readout hoisted (input-independent).
// Verdict: 256 single-hop flags; clean half -> write out; dirty half -> phase 2 (verbatim R7).

typedef short short8 __attribute__((ext_vector_type(8)));
typedef float f32x4 __attribute__((ext_vector_type(4)));

#define T_STEPS 250
#define BATCH   128
#define HID     1024
#define NCOL    4096
#define IND     700
#define ISZ     1724
#define KPAD    704
#define OUTD    20
#define NWG     256
#define WGT     256
#define UPB     5632      // 16B units per (t,half64) A block

// ws layout (bytes)
#define O_P1F   0                // u64[256] phase-1 flags (idx = rtile*64+ctile)
#define O_SUM   2048             // u64[2 parity][2 half][128 wg]
#define O_CHK   6144             // u64[2][2][128][16]
#define O_WST   71680            // f32 [1024][4096]
#define O_WXH   16848896         // bf16 [4096][704]
#define O_XH    22616064         // bf16 [250][2][5632][8] swizzled

// smem arena (phase-1/phase-2 alias deliberately; phase 2 restages everything)
#define SM_BP    0               // phase2: Wx^T panel 45568
#define SM_A2    45568           // phase2: ApreB 90112
#define SM_CURL2 135680          // phase2: C exchange 9216
#define SM_MTB   144896          // phase2: masks 8704
#define SM_TOTAL 153600
// phase1 overlay: Abuf = smem+0 (3 x 45056 = 135168); preg = smem+135168 (16384)

#define AGENT __HIP_MEMORY_SCOPE_AGENT

__device__ __forceinline__ float sigmoidf(float x) { return 1.0f / (1.0f + expf(-x)); }

__device__ __forceinline__ unsigned ldsLd(const unsigned* p) {
    return __hip_atomic_load(p, __ATOMIC_ACQUIRE, __HIP_MEMORY_SCOPE_WORKGROUP);
}
__device__ __forceinline__ void ldsSt(unsigned* p, unsigned v) {
    __hip_atomic_store(p, v, __ATOMIC_RELEASE, __HIP_MEMORY_SCOPE_WORKGROUP);
}

__device__ __forceinline__ void dma16(const void* g, void* l) {
    __builtin_amdgcn_global_load_lds(
        (const __attribute__((address_space(1))) unsigned int*)g,
        (__attribute__((address_space(3))) unsigned int*)l, 16, 0, 0);
}

// quad-lane sum (lanes xor 1, xor 2) via DPP quad_perm — pure VALU, no LDS pipe
__device__ __forceinline__ float qsum4(float v) {
    union { float f; int i; } a, b;
    a.f = v; b.i = __builtin_amdgcn_mov_dpp(a.i, 0xB1, 0xF, 0xF, true); v += b.f;  // xor 1
    a.f = v; b.i = __builtin_amdgcn_mov_dpp(a.i, 0x4E, 0xF, 0xF, true); v += b.f;  // xor 2
    return v;
}

// phase-1: each wave issues its 11 of the 44 1KB-units of a 32-row A slice
__device__ __forceinline__ void issueA2(const __hip_bfloat16* Xh, int t, int halfI,
                                        size_t subOff, uint8_t* dbuf, int wid, int lane) {
    const char* g = (const char*)Xh + ((size_t)(t * 2 + halfI)) * UPB * 16 + subOff;
    #pragma unroll
    for (int i = 0; i < 11; ++i) {
        int j = wid * 11 + i;
        dma16(g + (size_t)j * 1024 + (size_t)lane * 16, dbuf + j * 1024);
    }
}

// x -> Xh, pre-swizzled: unit q of block (t,half64) holds (row=q/88, k=((q%88)^(row&7))*8+e).
__global__ void prep_x(const float* __restrict__ x, __hip_bfloat16* __restrict__ Xh) {
    const int total = T_STEPS * 2 * UPB;
    for (int unit = blockIdx.x * blockDim.x + threadIdx.x; unit < total;
         unit += gridDim.x * blockDim.x) {
        int q   = unit % UPB;
        int blk = unit / UPB;
        int half = blk & 1, t = blk >> 1;
        int row = q / 88, m = q % 88;
        int k8  = m ^ (row & 7);
        int b   = half * 64 + row;
        const float* xp = x + ((long)b * T_STEPS + t) * IND + k8 * 8;
        short8 o;
        #pragma unroll
        for (int e = 0; e < 8; ++e) {
            int k = k8 * 8 + e;
            float v = (k < IND) ? xp[e] : 0.0f;
            union { __hip_bfloat16 h; short s; } u;
            u.h = __float2bfloat16(v);
            o[e] = u.s;
        }
        *(short8*)(Xh + (size_t)unit * 8) = o;
    }
}

__global__ void prep_w(const float* __restrict__ W, __hip_bfloat16* __restrict__ Wxh,
                       uint64_t* __restrict__ p1f, uint64_t* __restrict__ sums,
                       uint64_t* __restrict__ chunks) {
    if (blockIdx.x == 0) {       // zero exchange area every launch (replay + 0xAA poison)
        for (int i = threadIdx.x; i < 256; i += blockDim.x)
            __hip_atomic_store(&p1f[i], 0ull, __ATOMIC_RELAXED, AGENT);
        for (int i = threadIdx.x; i < 2 * 2 * 128; i += blockDim.x)
            __hip_atomic_store(&sums[i], 0ull, __ATOMIC_RELAXED, AGENT);
        for (int i = threadIdx.x; i < 2 * 2 * 128 * 16; i += blockDim.x)
            __hip_atomic_store(&chunks[i], 0ull, __ATOMIC_RELAXED, AGENT);
    }
    const int total = NCOL * KPAD;
    for (int idx = blockIdx.x * blockDim.x + threadIdx.x; idx < total; idx += gridDim.x * blockDim.x) {
        int k = idx % KPAD;
        int n = idx / KPAD;
        float v = (k < IND) ? W[(long)n * ISZ + k] : 0.0f;
        Wxh[idx] = __float2bfloat16(v);
    }
}

// Wst[h][n] = W[n][700+h]
__global__ __launch_bounds__(256) void prep_t(const float* __restrict__ W, float* __restrict__ Wst) {
    __shared__ float tile[32][33];
    const int h0 = blockIdx.x * 32, n0 = blockIdx.y * 32;
    const int tx = threadIdx.x, ty = threadIdx.y;
    #pragma unroll
    for (int j = 0; j < 32; j += 8)
        tile[ty + j][tx] = W[(long)(n0 + ty + j) * ISZ + IND + h0 + tx];
    __syncthreads();
    #pragma unroll
    for (int j = 0; j < 32; j += 8)
        Wst[(long)(h0 + ty + j) * NCOL + n0 + tx] = tile[tx][ty + j];
}

__global__ __launch_bounds__(256, 1) __attribute__((amdgpu_waves_per_eu(1, 1)))
void snn_scan(
    const __hip_bfloat16* __restrict__ Xh, const __hip_bfloat16* __restrict__ Wxh,
    const float* __restrict__ Wst, uint64_t* __restrict__ p1f, uint64_t* __restrict__ sums,
    uint64_t* __restrict__ chunks,
    const float* __restrict__ bvec, const float* __restrict__ tau_m, const float* __restrict__ tau_n,
    const float* __restrict__ Wr, const float* __restrict__ brv, const float* __restrict__ tau_r,
    const float* __restrict__ mem0, float* __restrict__ out)
{
    __shared__ __align__(16) char smem[SM_TOTAL];
    __shared__ uint32_t stageW[16];
    __shared__ uint64_t roSnap[16];
    __shared__ unsigned fPollDone[2], fStgw[2], fCorr[2];
    __shared__ unsigned fRoSnap, anySpkF, dirtyH[2];

    __hip_bfloat16* Bp    = (__hip_bfloat16*)(smem + SM_BP);
    uint8_t*        Abuf  = (uint8_t*)smem;                 // phase1: 3 x 45056
    float*          preg  = (float*)(smem + 135168);        // phase1: 2 parity x 8 slots x 1024B
    uint8_t*        Apre2 = (uint8_t*)(smem + SM_A2);
    float*          curL2 = (float*)(smem + SM_CURL2);
    uint8_t*        mTb   = (uint8_t*)(smem + SM_MTB);

    const int wg    = blockIdx.x;
    const int rtile = wg & 3;         // rows [rtile*32, +32)  (XCD-constant under round-robin)
    const int ctile = wg >> 2;        // cols [ctile*64, +64)
    const int tid   = threadIdx.x;
    const int lane  = tid & 63, wid = tid >> 6;
    const int colA  = lane & 15, kb8 = (lane >> 4) * 8;
    const int cg    = wid >> 1;       // col-group: cols [cg*32, +32) within WG
    const int p     = wid & 1;        // k-half: chunks [11p, 11p+11); owns row-tile p

    if (tid < 2) { fPollDone[tid] = 0; fStgw[tid] = 0; fCorr[tid] = 0; dirtyH[tid] = 0; }
    if (tid == 0) { fRoSnap = 0; anySpkF = 0; }

    // readout consts (o = lane) — shared by both phases
    float r_alpha = 0.f, r_bias = 0.f;
    const float* WrRow = Wr;
    if (wid == 0 && lane < 32) {
        int o = (lane < OUTD) ? lane : 0;
        r_alpha = sigmoidf(tau_r[o]);
        r_bias  = brv[o];
        WrRow   = Wr + o * HID;
    }
    const int roB1 = (ctile < 32) ? rtile * 32 + ctile : -1;

    // ---------------- phase-1 per-lane state (C-layout): 2 cols x 4 rows ----------------
    const int colG0 = ctile * 64 + cg * 32 + colA;        // tile i=0
    const int colG1 = colG0 + 16;                          // tile i=1
    const int rowB  = rtile * 32 + p * 16 + (lane >> 4) * 4;   // own row-tile = p
    float bt_[2], omb_[2], bias_[2], al_[2], oma_[2], dn[2][4], mem[2][4];
    {
        const int cG[2] = {colG0, colG1};
        #pragma unroll
        for (int i = 0; i < 2; ++i) {
            bt_[i]   = sigmoidf(tau_n[cG[i]]);
            omb_[i]  = 1.0f - bt_[i];
            bias_[i] = bvec[cG[i]];
            al_[i]   = sigmoidf(tau_m[cG[i] >> 2]);
            oma_[i]  = 1.0f - al_[i];
            #pragma unroll
            for (int j = 0; j < 4; ++j) {
                dn[i][j]  = 0.0f;
                mem[i][j] = mem0[(rowB + j) * HID + (cG[i] >> 2)];
            }
        }
    }

    // ---------------- B panel -> registers: 22 frags = 88 VGPR (resident) ----------------
    short8 Breg[22];
    #pragma unroll
    for (int j = 0; j < 11; ++j) {
        Breg[2 * j]     = *(const short8*)(Wxh + (long)colG0 * KPAD + (11 * p + j) * 32 + kb8);
        Breg[2 * j + 1] = *(const short8*)(Wxh + (long)colG1 * KPAD + (11 * p + j) * 32 + kb8);
    }
    asm volatile("s_waitcnt vmcnt(0)" ::: "memory");
    __builtin_amdgcn_sched_barrier(0);
    #pragma unroll
    for (int i = 0; i < 22; ++i) asm volatile("" : "+v"(Breg[i]));

    // ---------------- A pipeline prologue ----------------
    const int    halfI  = rtile >> 1;
    const size_t subOff = (size_t)(rtile & 1) * 45056;
    issueA2(Xh, 0, halfI, subOff, Abuf, wid, lane);
    issueA2(Xh, 1, halfI, subOff, Abuf + 45056, wid, lane);
    asm volatile("s_waitcnt vmcnt(11)" ::: "memory");   // own buf0 units done
    __syncthreads();                                     // all waves' buf0 done

    // ================= PHASE 1: optimistic free-run =================
    float memmax = -1e30f;
    for (int t = 0; t < T_STEPS; ++t) {
        // 1. issue DMA[t+2]
        if (t + 2 < T_STEPS)
            issueA2(Xh, t + 2, halfI, subOff, Abuf + ((t + 2) % 3) * 45056, wid, lane);

        // 2. MFMA: 2 col-tiles x 2 row-tiles x 11 k-chunks, B from regs
        f32x4 aA0 = {0,0,0,0}, aB0 = {0,0,0,0}, aA1 = {0,0,0,0}, aB1 = {0,0,0,0};
        const uint8_t* Ab = Abuf + (t % 3) * 45056;
        #pragma unroll
        for (int j = 0; j < 11; ++j) {
            int c = 11 * p + j;
            int u = (c * 4 + (lane >> 4)) ^ (lane & 7);
            const uint8_t* base = Ab + colA * 1408 + u * 16;
            short8 a0 = *(const short8*)(base);            // rows 0-15
            short8 a1 = *(const short8*)(base + 22528);    // rows 16-31
            aA0 = __builtin_amdgcn_mfma_f32_16x16x32_bf16(a0, Breg[2 * j],     aA0, 0, 0, 0);
            aB0 = __builtin_amdgcn_mfma_f32_16x16x32_bf16(a0, Breg[2 * j + 1], aB0, 0, 0, 0);
            aA1 = __builtin_amdgcn_mfma_f32_16x16x32_bf16(a1, Breg[2 * j],     aA1, 0, 0, 0);
            aB1 = __builtin_amdgcn_mfma_f32_16x16x32_bf16(a1, Breg[2 * j + 1], aB1, 0, 0, 0);
        }

        // 3. symmetric partial exchange: send row-tile (1-p), keep row-tile p
        f32x4 own0, own1, snd0, snd1;
        if (p == 0) { own0 = aA0; own1 = aB0; snd0 = aA1; snd1 = aB1; }
        else        { own0 = aA1; own1 = aB1; snd0 = aA0; snd1 = aB0; }
        {
            float* w0 = preg + (t & 1) * 2048 + ((cg * 2 + (1 - p)) * 2 + 0) * 256 + lane * 4;
            float* w1 = preg + (t & 1) * 2048 + ((cg * 2 + (1 - p)) * 2 + 1) * 256 + lane * 4;
            *(f32x4*)w0 = snd0;
            *(f32x4*)w1 = snd1;
        }
        if (t + 2 < T_STEPS) asm volatile("s_waitcnt vmcnt(11) lgkmcnt(0)" ::: "memory");
        else                 asm volatile("s_waitcnt vmcnt(0) lgkmcnt(0)" ::: "memory");
        __builtin_amdgcn_sched_barrier(0);
        __builtin_amdgcn_s_barrier();

        // 4. combine + zero-spike update in C-layout (lane = column; quad-dpp branch sum)
        {
            const float* r0 = preg + (t & 1) * 2048 + ((cg * 2 + p) * 2 + 0) * 256 + lane * 4;
            const float* r1 = preg + (t & 1) * 2048 + ((cg * 2 + p) * 2 + 1) * 256 + lane * 4;
            f32x4 cs0 = own0 + *(const f32x4*)r0;
            f32x4 cs1 = own1 + *(const f32x4*)r1;
            #pragma unroll
            for (int j = 0; j < 4; ++j) {
                float d0 = bt_[0] * dn[0][j] + omb_[0] * (cs0[j] + bias_[0]);
                float d1 = bt_[1] * dn[1][j] + omb_[1] * (cs1[j] + bias_[1]);
                dn[0][j] = d0; dn[1][j] = d1;
                float l0 = qsum4(d0), l1 = qsum4(d1);
                float m0 = al_[0] * mem[0][j] + oma_[0] * l0;   // VTH=1; spk==0 assumed
                float m1 = al_[1] * mem[1][j] + oma_[1] * l1;
                mem[0][j] = m0; mem[1][j] = m1;
                memmax = fmaxf(memmax, fmaxf(m0, m1));
            }
        }
    }

    // ---------------- verdict ----------------
    if (__any(memmax > 1.0f) && lane == 0) anySpkF = 1u;
    __syncthreads();
    if (tid == 0)
        __hip_atomic_store(p1f + rtile * 64 + ctile,
                           (1ull << 32) | (uint64_t)anySpkF, __ATOMIC_RELAXED, AGENT);
    {
        const uint64_t* fp = p1f + tid;   // 256 threads <-> 256 flags
        uint64_t v;
        for (;;) {
            v = __hip_atomic_load(fp, __ATOMIC_RELAXED, AGENT);
            if ((unsigned)(v >> 32) == 1u) break;
            __builtin_amdgcn_s_sleep(1);
        }
        if ((unsigned)v != 0u) dirtyH[tid >> 7] = 1u;   // idx<128 <=> rows 0..63
    }
    __syncthreads();

    // clean half: hoisted readout (input-independent under zero spikes) + write out
    if (!dirtyH[rtile >> 1] && wid == 0 && roB1 >= 0 && lane < 32) {
        float rr = 0.f, racc = 0.f;
        for (int t = 0; t < T_STEPS; ++t) {
            rr = r_alpha * rr + (1.0f - r_alpha) * r_bias;   // rsum = 0
            float vmax = (lane < OUTD) ? rr : -__builtin_inff();
            #pragma unroll
            for (int d = 16; d > 0; d >>= 1) vmax = fmaxf(vmax, __shfl_xor(vmax, d, 32));
            float e = (lane < OUTD) ? expf(rr - vmax) : 0.f;
            float ss = e;
            #pragma unroll
            for (int d = 16; d > 0; d >>= 1) ss += __shfl_xor(ss, d, 32);
            if (t >= 1) racc += e / ss;   // WARMUP=0
        }
        if (lane < OUTD) out[roB1 * OUTD + lane] = racc;
    }
    if (!dirtyH[wg >> 7]) return;

    // ================= PHASE 2: synchronous fallback (R7 algorithm, tags +1) ============
    float r_rmem = 0.f, r_acc = 0.f;
    const int w2    = wg & 127;
    const int bhalf = wg >> 7;
    const int bbase = bhalf * 64;
    const int c0    = w2 * 32;
    const int i0    = w2 * 8;
    const int roB2  = (wg < 64) ? wg : ((wg >= 128 && wg < 192) ? wg - 64 : -1);

    // deferred staging: Bp (vectorized) + mTb zero
    for (int idx = tid; idx < 32 * 88; idx += WGT) {
        int col = idx / 88, m = idx % 88;
        *(short8*)(Bp + col * 712 + m * 8) = *(const short8*)(Wxh + (long)(c0 + col) * KPAD + m * 8);
    }
    for (int idx = tid; idx < 64 * 136 / 4; idx += WGT)
        ((uint32_t*)mTb)[idx] = 0u;

    const int mwid = wid - 2;
    const int st   = tid - 128;
    const int r2   = st >> 1;
    const int half = st & 1;
    float dn2[16], bt2[16], omb2[16], bias2[16], alph2[4], oma2[4], mem2[4], spk2[4];
    if (wid >= 2) {
        const int b2 = bbase + r2;
        #pragma unroll
        for (int n = 0; n < 4; ++n) {
            int i = i0 + half * 4 + n;
            alph2[n] = sigmoidf(tau_m[i]);
            oma2[n]  = 1.0f - alph2[n];
            mem2[n]  = mem0[b2 * HID + i];
            spk2[n]  = 0.0f;
            #pragma unroll
            for (int j = 0; j < 4; ++j) {
                int idx = n * 4 + j;
                bt2[idx]   = sigmoidf(tau_n[i * 4 + j]);
                omb2[idx]  = 1.0f - bt2[idx];
                bias2[idx] = bvec[i * 4 + j];
                dn2[idx]   = 0.0f;
            }
        }
    }
    const int trRow = mwid * 32;
    const int rb2   = trRow + (lane & 15);
    const int sw2   = rb2 & 7;
    uint8_t* dst2   = Apre2 + mwid * 45056;

    if (wid >= 2) {
        const char* gsrc = (const char*)Xh + ((size_t)bhalf * UPB) * 16 + (size_t)mwid * 45056;
        #pragma unroll
        for (int i = 0; i < 44; ++i)
            dma16(gsrc + i * 1024 + lane * 16, dst2 + i * 1024);
    }
    asm volatile("s_waitcnt vmcnt(0)" ::: "memory");
    __syncthreads();

    if (wid < 2) {
        // ---- poll waves ----
        const int plane = tid;
        for (int k = 1; k <= T_STEPS; ++k) {
            const size_t base = ((size_t)((k - 1) & 1) * 2 + bhalf) * 128 + plane;
            const unsigned want = (unsigned)(k + 1);
            uint64_t v;
            for (;;) {
                v = __hip_atomic_load(sums + base, __ATOMIC_RELAXED, AGENT);
                if ((unsigned)(v >> 32) == want) break;
                __builtin_amdgcn_s_sleep(1);
            }
            unsigned mysum = (unsigned)v;
            if (mysum) {
                if (wid == 1)
                    while (ldsLd(&fRoSnap) < (unsigned)(k - 1)) {}
                const uint64_t* rec = chunks + base * 16;
                uint8_t* col = mTb + plane;
                unsigned pend = mysum;
                while (pend) {
                    int c = __builtin_ctz(pend);
                    uint64_t cv = __hip_atomic_load(rec + c, __ATOMIC_RELAXED, AGENT);
                    if ((unsigned)(cv >> 32) == want) {
                        pend &= pend - 1;
                        unsigned pay = (unsigned)cv;
                        col[(4 * c + 0) * 136] = (uint8_t)(pay);
                        col[(4 * c + 1) * 136] = (uint8_t)(pay >> 8);
                        col[(4 * c + 2) * 136] = (uint8_t)(pay >> 16);
                        col[(4 * c + 3) * 136] = (uint8_t)(pay >> 24);
                    } else {
                        __builtin_amdgcn_s_sleep(1);
                    }
                }
            }
            const bool anyW = __any(mysum != 0u);
            if (lane == 0)
                ldsSt(&fPollDone[wid], ((unsigned)k << 1) | (anyW ? 1u : 0u));

            if (wid == 0) {
                while ((ldsLd(&fPollDone[1]) >> 1) < (unsigned)k) {}
                if (roB2 >= 0 && lane < 16)
                    roSnap[lane] = ((const uint64_t*)(mTb + (roB2 & 63) * 136))[lane];
                asm volatile("s_waitcnt lgkmcnt(0)" ::: "memory");
                if (lane == 0) ldsSt(&fRoSnap, (unsigned)k);
                if (roB2 >= 0 && lane < 32) {
                    float rsum = 0.f;
                    #pragma unroll 4
                    for (int q = 0; q < 16; ++q) {
                        uint64_t mword = roSnap[q];
                        while (mword) {
                            int h = (q << 6) + __builtin_ctzll(mword);
                            mword &= mword - 1;
                            rsum += WrRow[h];
                        }
                    }
                    r_rmem = r_alpha * r_rmem + (1.0f - r_alpha) * (rsum + r_bias);
                    float vmax = (lane < OUTD) ? r_rmem : -__builtin_inff();
                    #pragma unroll
                    for (int d = 16; d > 0; d >>= 1) vmax = fmaxf(vmax, __shfl_xor(vmax, d, 32));
                    float e = (lane < OUTD) ? expf(r_rmem - vmax) : 0.f;
                    float ssum = e;
                    #pragma unroll
                    for (int d = 16; d > 0; d >>= 1) ssum += __shfl_xor(ssum, d, 32);
                    if (k >= 2) r_acc += e / ssum;
                }
            }
        }
        if (wid == 0 && roB2 >= 0 && lane < OUTD) out[roB2 * OUTD + lane] = r_acc;
    } else {
        // ---- compute waves ----
        const float* clp = curL2 + r2 * 36 + half * 16;
        for (int t = 0; t < T_STEPS; ++t) {
            f32x4 a00 = {0,0,0,0}, a01 = {0,0,0,0}, a10 = {0,0,0,0}, a11 = {0,0,0,0};
            #pragma unroll
            for (int k0 = 0; k0 < KPAD; k0 += 32) {
                int k8 = (k0 >> 3) + (lane >> 4);
                short8 f0 = *(const short8*)&Apre2[(((rb2)      * 88 + (k8 ^ sw2)) << 4)];
                short8 f1 = *(const short8*)&Apre2[(((rb2 + 16) * 88 + (k8 ^ sw2)) << 4)];
                short8 b0 = *(const short8*)(&Bp[(colA) * 712 + k0 + kb8]);
                short8 b1 = *(const short8*)(&Bp[(16 + colA) * 712 + k0 + kb8]);
                a00 = __builtin_amdgcn_mfma_f32_16x16x32_bf16(f0, b0, a00, 0, 0, 0);
                a01 = __builtin_amdgcn_mfma_f32_16x16x32_bf16(f0, b1, a01, 0, 0, 0);
                a10 = __builtin_amdgcn_mfma_f32_16x16x32_bf16(f1, b0, a10, 0, 0, 0);
                a11 = __builtin_amdgcn_mfma_f32_16x16x32_bf16(f1, b1, a11, 0, 0, 0);
            }
            asm volatile("s_waitcnt lgkmcnt(0)" ::: "memory");
            __builtin_amdgcn_sched_barrier(0);
            if (t + 1 < T_STEPS) {
                const char* gsrc = (const char*)Xh
                    + (((size_t)(t + 1) * 2 + bhalf) * UPB) * 16 + (size_t)mwid * 45056;
                #pragma unroll
                for (int i = 0; i < 44; ++i)
                    dma16(gsrc + i * 1024 + lane * 16, dst2 + i * 1024);
            }
            {
                const int crow0 = trRow + ((lane >> 4) << 2);
                #pragma unroll
                for (int j = 0; j < 4; ++j) {
                    curL2[(crow0 + j) * 36 + colA]           = a00[j];
                    curL2[(crow0 + j) * 36 + 16 + colA]      = a01[j];
                    curL2[(crow0 + 16 + j) * 36 + colA]      = a10[j];
                    curL2[(crow0 + 16 + j) * 36 + 16 + colA] = a11[j];
                }
            }
            asm volatile("s_waitcnt lgkmcnt(0)" ::: "memory");
            __builtin_amdgcn_sched_barrier(0);

            f32x4 cv0 = *(const f32x4*)(clp + 0);
            f32x4 cv1 = *(const f32x4*)(clp + 4);
            f32x4 cv2 = *(const f32x4*)(clp + 8);
            f32x4 cv3 = *(const f32x4*)(clp + 12);
            float cl[16];
            #pragma unroll
            for (int e = 0; e < 4; ++e) {
                cl[e] = cv0[e]; cl[4 + e] = cv1[e]; cl[8 + e] = cv2[e]; cl[12 + e] = cv3[e];
            }
            float memS[4], spkS[4];
            #pragma unroll
            for (int n = 0; n < 4; ++n) {
                float lin = 0.f;
                #pragma unroll
                for (int j = 0; j < 4; ++j) {
                    int idx = n * 4 + j;
                    dn2[idx] = bt2[idx] * dn2[idx] + omb2[idx] * (cl[idx] + bias2[idx]);
                    lin += dn2[idx];
                }
                memS[n] = alph2[n] * mem2[n] + oma2[n] * lin - spk2[n];
                spkS[n] = (memS[n] > 1.0f) ? 1.0f : 0.0f;
            }
            unsigned nib = 0;
            #pragma unroll
            for (int n = 0; n < 4; ++n) nib |= (spkS[n] != 0.f ? 1u : 0u) << (half * 4 + n);
            nib |= (unsigned)__shfl_xor((int)nib, 1);
            if (half == 0) ((uint8_t*)stageW)[r2] = (uint8_t)nib;
            if (lane == 0) ldsSt(&fStgw[mwid], (unsigned)(t + 1));

            bool anySpk = false;
            if (t > 0) {
                unsigned p0, p1;
                do { p0 = ldsLd(&fPollDone[0]); } while ((p0 >> 1) < (unsigned)t);
                do { p1 = ldsLd(&fPollDone[1]); } while ((p1 >> 1) < (unsigned)t);
                anySpk = ((p0 | p1) & 1u) != 0u;
            }
            if (anySpk) {
                float recv[16];
                #pragma unroll
                for (int e = 0; e < 16; ++e) recv[e] = 0.f;
                const float* Wb = Wst + c0 + half * 16;
                const uint64_t* mrow = (const uint64_t*)(mTb + r2 * 136);
                for (int q = 0; q < 16; ++q) {
                    uint64_t mword = mrow[q];
                    while (mword) {
                        int h = (q << 6) + __builtin_ctzll(mword);
                        mword &= mword - 1;
                        const f32x4* wv = (const f32x4*)(Wb + (long)h * NCOL);
                        f32x4 w0 = wv[0], w1 = wv[1], w2v = wv[2], w3 = wv[3];
                        #pragma unroll
                        for (int e = 0; e < 4; ++e) {
                            recv[e] += w0[e]; recv[4 + e] += w1[e];
                            recv[8 + e] += w2v[e]; recv[12 + e] += w3[e];
                        }
                    }
                }
                #pragma unroll
                for (int n = 0; n < 4; ++n) {
                    float cs = 0.f;
                    #pragma unroll
                    for (int j = 0; j < 4; ++j) {
                        int idx = n * 4 + j;
                        float ad = omb2[idx] * recv[idx];
                        dn2[idx] += ad; cs += ad;
                    }
                    memS[n] += oma2[n] * cs;
                    spkS[n] = (memS[n] > 1.0f) ? 1.0f : 0.0f;
                }
                unsigned nib2 = 0;
                #pragma unroll
                for (int n = 0; n < 4; ++n) nib2 |= (spkS[n] != 0.f ? 1u : 0u) << (half * 4 + n);
                nib2 |= (unsigned)__shfl_xor((int)nib2, 1);
                if (half == 0) ((uint8_t*)stageW)[r2] = (uint8_t)nib2;
                if (roB2 >= 0) while (ldsLd(&fRoSnap) < (unsigned)t) {}
                uint64_t* mz = (uint64_t*)(mTb + r2 * 136) + half * 8;
                #pragma unroll
                for (int e = 0; e < 8; ++e) mz[e] = 0;
                if (lane == 0) ldsSt(&fCorr[mwid], (unsigned)(t + 1));
            }
            #pragma unroll
            for (int n = 0; n < 4; ++n) { mem2[n] = memS[n]; spk2[n] = spkS[n]; }

            if (mwid == 0) {
                while (ldsLd(&fStgw[1]) < (unsigned)(t + 1)) {}
                if (anySpk) while (ldsLd(&fCorr[1]) < (unsigned)(t + 1)) {}
                unsigned pay = (lane < 16) ? stageW[lane] : 0u;
                const size_t pbase = ((size_t)(t & 1) * 2 + bhalf) * 128 + w2;
                if (lane < 16 && pay)
                    __hip_atomic_store(chunks + pbase * 16 + lane,
                                       ((uint64_t)(unsigned)(t + 2) << 32) | (uint64_t)pay,
                                       __ATOMIC_RELAXED, AGENT);
                uint64_t bal = __ballot(pay != 0u);
                if (lane == 0)
                    __hip_atomic_store(sums + pbase,
                                       ((uint64_t)(unsigned)(t + 2) << 32) | (uint64_t)(bal & 0xFFFFull),
                                       __ATOMIC_RELAXED, AGENT);
            }
            asm volatile("s_waitcnt vmcnt(0)" ::: "memory");
        }
    }
}

extern "C" void kernel_launch(void* const* d_in, const int* in_sizes, int n_in,
                              void* d_out, int out_size, void* d_ws, size_t ws_size,
                              hipStream_t stream) {
    (void)in_sizes; (void)n_in; (void)out_size; (void)ws_size;
    const float* x     = (const float*)d_in[0];
    const float* W     = (const float*)d_in[1];
    const float* bv    = (const float*)d_in[2];
    const float* tau_m = (const float*)d_in[3];
    const float* tau_n = (const float*)d_in[4];
    const float* Wr    = (const float*)d_in[5];
    const float* br    = (const float*)d_in[6];
    const float* tau_r = (const float*)d_in[7];
    const float* mem0  = (const float*)d_in[8];

    char* ws = (char*)d_ws;
    uint64_t*        p1flag = (uint64_t*)(ws + O_P1F);
    uint64_t*        sums   = (uint64_t*)(ws + O_SUM);
    uint64_t*        chunks = (uint64_t*)(ws + O_CHK);
    float*           Wst    = (float*)(ws + O_WST);
    __hip_bfloat16*  Wxh    = (__hip_bfloat16*)(ws + O_WXH);
    __hip_bfloat16*  Xh     = (__hip_bfloat16*)(ws + O_XH);

    prep_x<<<2048, 256, 0, stream>>>(x, Xh);
    prep_w<<<2048, 256, 0, stream>>>(W, Wxh, p1flag, sums, chunks);
    dim3 g3(32, 128), b3(32, 8);
    prep_t<<<g3, b3, 0, stream>>>(W, Wst);
    snn_scan<<<NWG, WGT, 0, stream>>>(Xh, Wxh, Wst, p1flag, sums, chunks,
                                      bv, tau_m, tau_n, Wr, br, tau_r, mem0, (float*)d_out);
}

// Round 13
// 452.094 us; speedup vs baseline: 1.2404x; 1.2402x over previous
//
#include <hip/hip_runtime.h>
#include <hip/hip_bf16.h>
#include <stdint.h>

// DH-SNN forward: two-phase optimistic execution, v4 — occupancy-split.
// p1_scan (512 WGs, 2/CU): lean zero-spike free-run. WG = 16 rows (rtile=wg&7 == XCD) x 64 cols.
//   Wave (cg,p): 32 cols x k-half -> B = 22 frags = 88 VGPR resident; 11 A-reads + 4 exchange
//   LDS ops/step; A slice (22.5KB/step) triple-buffered via counted-vmcnt DMA. 2 waves/SIMD
//   hide the latency chains that pinned R8-R12 at 2us/step (1 wave/SIMD, no TLP).
//   Output: per-WG violation flag only.
// p2_fallback (256 WGs, separate launch): reads flags (stream-ordered), writes hoisted
//   input-independent readout for clean halves, early-exits; dirty half runs verbatim R7
//   synchronous algorithm (tags +1, own 153KB LDS arena).

typedef short short8 __attribute__((ext_vector_type(8)));
typedef float f32x4 __attribute__((ext_vector_type(4)));

#define T_STEPS 250
#define BATCH   128
#define HID     1024
#define NCOL    4096
#define IND     700
#define ISZ     1724
#define KPAD    704
#define OUTD    20
#define WGT     256
#define UPB     5632      // 16B units per (t,half64) A block

// ws layout (bytes)
#define O_P1F   0                // u64[512] phase-1 flags (idx = p1 wg)
#define O_SUM   4096             // u64[2 parity][2 half][128 wg]
#define O_CHK   8192             // u64[2][2][128][16]
#define O_WST   73728            // f32 [1024][4096]
#define O_WXH   16850944         // bf16 [4096][704]
#define O_XH    22618112         // bf16 [250][2][5632][8] swizzled (end ~67.7MB)

// p2 smem arena
#define SM_BP    0               // Wx^T panel 45568
#define SM_A2    45568           // ApreB 90112
#define SM_CURL2 135680          // C exchange 9216
#define SM_MTB   144896          // masks 8704
#define SM_TOTAL 153600

#define AGENT __HIP_MEMORY_SCOPE_AGENT

__device__ __forceinline__ float sigmoidf(float x) { return 1.0f / (1.0f + expf(-x)); }

__device__ __forceinline__ unsigned ldsLd(const unsigned* p) {
    return __hip_atomic_load(p, __ATOMIC_ACQUIRE, __HIP_MEMORY_SCOPE_WORKGROUP);
}
__device__ __forceinline__ void ldsSt(unsigned* p, unsigned v) {
    __hip_atomic_store(p, v, __ATOMIC_RELEASE, __HIP_MEMORY_SCOPE_WORKGROUP);
}

__device__ __forceinline__ void dma16(const void* g, void* l) {
    __builtin_amdgcn_global_load_lds(
        (const __attribute__((address_space(1))) unsigned int*)g,
        (__attribute__((address_space(3))) unsigned int*)l, 16, 0, 0);
}

// quad-lane sum (lanes xor 1, xor 2) via DPP quad_perm — pure VALU
__device__ __forceinline__ float qsum4(float v) {
    union { float f; int i; } a, b;
    a.f = v; b.i = __builtin_amdgcn_mov_dpp(a.i, 0xB1, 0xF, 0xF, true); v += b.f;  // xor 1
    a.f = v; b.i = __builtin_amdgcn_mov_dpp(a.i, 0x4E, 0xF, 0xF, true); v += b.f;  // xor 2
    return v;
}

// x -> Xh, pre-swizzled: unit q of block (t,half64) holds (row=q/88, k=((q%88)^(row&7))*8+e).
__global__ void prep_x(const float* __restrict__ x, __hip_bfloat16* __restrict__ Xh) {
    const int total = T_STEPS * 2 * UPB;
    for (int unit = blockIdx.x * blockDim.x + threadIdx.x; unit < total;
         unit += gridDim.x * blockDim.x) {
        int q   = unit % UPB;
        int blk = unit / UPB;
        int half = blk & 1, t = blk >> 1;
        int row = q / 88, m = q % 88;
        int k8  = m ^ (row & 7);
        int b   = half * 64 + row;
        const float* xp = x + ((long)b * T_STEPS + t) * IND + k8 * 8;
        short8 o;
        #pragma unroll
        for (int e = 0; e < 8; ++e) {
            int k = k8 * 8 + e;
            float v = (k < IND) ? xp[e] : 0.0f;
            union { __hip_bfloat16 h; short s; } u;
            u.h = __float2bfloat16(v);
            o[e] = u.s;
        }
        *(short8*)(Xh + (size_t)unit * 8) = o;
    }
}

__global__ void prep_w(const float* __restrict__ W, __hip_bfloat16* __restrict__ Wxh,
                       uint64_t* __restrict__ p1f, uint64_t* __restrict__ sums,
                       uint64_t* __restrict__ chunks) {
    if (blockIdx.x == 0) {       // zero exchange area every launch (replay + 0xAA poison)
        for (int i = threadIdx.x; i < 512; i += blockDim.x)
            __hip_atomic_store(&p1f[i], 0ull, __ATOMIC_RELAXED, AGENT);
        for (int i = threadIdx.x; i < 2 * 2 * 128; i += blockDim.x)
            __hip_atomic_store(&sums[i], 0ull, __ATOMIC_RELAXED, AGENT);
        for (int i = threadIdx.x; i < 2 * 2 * 128 * 16; i += blockDim.x)
            __hip_atomic_store(&chunks[i], 0ull, __ATOMIC_RELAXED, AGENT);
    }
    const int total = NCOL * KPAD;
    for (int idx = blockIdx.x * blockDim.x + threadIdx.x; idx < total; idx += gridDim.x * blockDim.x) {
        int k = idx % KPAD;
        int n = idx / KPAD;
        float v = (k < IND) ? W[(long)n * ISZ + k] : 0.0f;
        Wxh[idx] = __float2bfloat16(v);
    }
}

// Wst[h][n] = W[n][700+h]
__global__ __launch_bounds__(256) void prep_t(const float* __restrict__ W, float* __restrict__ Wst) {
    __shared__ float tile[32][33];
    const int h0 = blockIdx.x * 32, n0 = blockIdx.y * 32;
    const int tx = threadIdx.x, ty = threadIdx.y;
    #pragma unroll
    for (int j = 0; j < 32; j += 8)
        tile[ty + j][tx] = W[(long)(n0 + ty + j) * ISZ + IND + h0 + tx];
    __syncthreads();
    #pragma unroll
    for (int j = 0; j < 32; j += 8)
        Wst[(long)(h0 + ty + j) * NCOL + n0 + tx] = tile[tx][ty + j];
}

// ======================= p1: lean optimistic free-run (512 WGs, 2/CU) =======================
__global__ __launch_bounds__(256, 2) void p1_scan(
    const __hip_bfloat16* __restrict__ Xh, const __hip_bfloat16* __restrict__ Wxh,
    const float* __restrict__ bvec, const float* __restrict__ tau_m,
    const float* __restrict__ tau_n, const float* __restrict__ mem0,
    uint64_t* __restrict__ p1f)
{
    __shared__ __align__(16) uint8_t Abuf[3 * 22528];   // 67584 B, triple-buffered A slice
    __shared__ __align__(16) float preg[8 * 256];       // 8192 B exchange [cg][dst p][frag]
    __shared__ unsigned anySpkF;

    const int wg    = blockIdx.x;        // 0..511
    const int rtile = wg & 7;            // batch rows [rtile*16,+16)  (== XCD round-robin)
    const int ctile = wg >> 3;           // cols [ctile*64,+64)
    const int tid   = threadIdx.x;
    const int lane  = tid & 63, wid = tid >> 6;
    const int colA  = lane & 15, kb8 = (lane >> 4) * 8;
    const int cg    = wid >> 1;          // col half: cols [cg*32,+32) within WG
    const int p     = wid & 1;           // k half: chunks [11p, 11p+11)

    if (tid == 0) anySpkF = 0u;

    // per-lane state (MFMA C-layout): 2 cols x 4 rows
    const int colG0 = ctile * 64 + cg * 32 + colA;
    const int colG1 = colG0 + 16;
    const int rowB  = rtile * 16 + (lane >> 4) * 4;
    float bt_[2], omb_[2], bias_[2], al_[2], oma_[2], dn[2][4], mem_[2][4];
    {
        const int cG[2] = {colG0, colG1};
        #pragma unroll
        for (int i = 0; i < 2; ++i) {
            bt_[i]   = sigmoidf(tau_n[cG[i]]);
            omb_[i]  = 1.0f - bt_[i];
            bias_[i] = bvec[cG[i]];
            al_[i]   = sigmoidf(tau_m[cG[i] >> 2]);
            oma_[i]  = 1.0f - al_[i];
            #pragma unroll
            for (int j = 0; j < 4; ++j) {
                dn[i][j]   = 0.0f;
                mem_[i][j] = mem0[(rowB + j) * HID + (cG[i] >> 2)];
            }
        }
    }

    // B panel -> registers: 22 frags = 88 VGPR
    short8 Breg[22];
    #pragma unroll
    for (int j = 0; j < 11; ++j) {
        Breg[2 * j]     = *(const short8*)(Wxh + (long)colG0 * KPAD + (11 * p + j) * 32 + kb8);
        Breg[2 * j + 1] = *(const short8*)(Wxh + (long)colG1 * KPAD + (11 * p + j) * 32 + kb8);
    }
    asm volatile("s_waitcnt vmcnt(0)" ::: "memory");
    __builtin_amdgcn_sched_barrier(0);
    #pragma unroll
    for (int i = 0; i < 22; ++i) asm volatile("" : "+v"(Breg[i]));

    // A DMA: 22 x 1KB units per slice; waves 0,1 take 6 units, waves 2,3 take 5
    const size_t sliceBase = (size_t)(rtile >> 2) * 90112 + (size_t)(rtile & 3) * 22528;
    const int dstart = (wid < 2) ? wid * 6 : 12 + (wid - 2) * 5;
    const int dcnt   = (wid < 2) ? 6 : 5;
    const char* XhB  = (const char*)Xh;

    // prologue: t=0 and t=1
    #pragma unroll
    for (int i = 0; i < 6; ++i)
        if (i < dcnt)
            dma16(XhB + sliceBase + (size_t)(dstart + i) * 1024 + (size_t)lane * 16,
                  Abuf + (dstart + i) * 1024);
    #pragma unroll
    for (int i = 0; i < 6; ++i)
        if (i < dcnt)
            dma16(XhB + sliceBase + 180224 + (size_t)(dstart + i) * 1024 + (size_t)lane * 16,
                  Abuf + 22528 + (dstart + i) * 1024);
    asm volatile("s_waitcnt vmcnt(5)" ::: "memory");   // batch0 complete for all waves
    __builtin_amdgcn_sched_barrier(0);
    __syncthreads();

    float memmax = -1e30f;
    const int rl = lane & 15;
    const int sw = rl & 7;
    for (int t = 0; t < T_STEPS; ++t) {
        // 1. issue DMA[t+2]
        if (t + 2 < T_STEPS) {
            const char* g = XhB + sliceBase + (size_t)(t + 2) * 180224;
            uint8_t* d = Abuf + ((t + 2) % 3) * 22528;
            #pragma unroll
            for (int i = 0; i < 6; ++i)
                if (i < dcnt)
                    dma16(g + (size_t)(dstart + i) * 1024 + (size_t)lane * 16,
                          d + (dstart + i) * 1024);
        }

        // 2. MFMA: 2 col-tiles x 11 k-chunks (own k-half), B from regs
        f32x4 acc0 = {0,0,0,0}, acc1 = {0,0,0,0};
        const uint8_t* Ab = Abuf + (t % 3) * 22528;
        #pragma unroll
        for (int j = 0; j < 11; ++j) {
            int k8 = (11 * p + j) * 4 + (lane >> 4);
            short8 a = *(const short8*)(Ab + ((rl * 88 + (k8 ^ sw)) << 4));
            acc0 = __builtin_amdgcn_mfma_f32_16x16x32_bf16(a, Breg[2 * j],     acc0, 0, 0, 0);
            acc1 = __builtin_amdgcn_mfma_f32_16x16x32_bf16(a, Breg[2 * j + 1], acc1, 0, 0, 0);
        }

        // 3. symmetric k-half exchange: send both frags to partner (cg, 1-p)
        {
            float* w0 = preg + ((cg * 2 + (1 - p)) * 2 + 0) * 256 + lane * 4;
            *(f32x4*)w0         = acc0;
            *(f32x4*)(w0 + 256) = acc1;
        }
        asm volatile("s_waitcnt vmcnt(5) lgkmcnt(0)" ::: "memory");  // buf[t+1] done; writes visible
        __builtin_amdgcn_sched_barrier(0);
        __builtin_amdgcn_s_barrier();

        // 4. combine + zero-spike update in C-layout
        f32x4 cs0, cs1;
        {
            const float* r0 = preg + ((cg * 2 + p) * 2 + 0) * 256 + lane * 4;
            cs0 = acc0 + *(const f32x4*)r0;
            cs1 = acc1 + *(const f32x4*)(r0 + 256);
        }
        #pragma unroll
        for (int j = 0; j < 4; ++j) {
            float d0 = bt_[0] * dn[0][j] + omb_[0] * (cs0[j] + bias_[0]);
            float d1 = bt_[1] * dn[1][j] + omb_[1] * (cs1[j] + bias_[1]);
            dn[0][j] = d0; dn[1][j] = d1;
            float l0 = qsum4(d0), l1 = qsum4(d1);
            float m0 = al_[0] * mem_[0][j] + oma_[0] * l0;   // VTH=1; spk==0 assumed
            float m1 = al_[1] * mem_[1][j] + oma_[1] * l1;
            mem_[0][j] = m0; mem_[1][j] = m1;
            memmax = fmaxf(memmax, fmaxf(m0, m1));
        }
        asm volatile("s_waitcnt lgkmcnt(0)" ::: "memory");   // preg reads retired
        __builtin_amdgcn_sched_barrier(0);
        __builtin_amdgcn_s_barrier();                        // reads done before next write
    }

    if (__any(memmax > 1.0f) && lane == 0) anySpkF = 1u;
    __syncthreads();
    if (tid == 0)
        __hip_atomic_store(p1f + wg, (1ull << 32) | (uint64_t)anySpkF,
                           __ATOMIC_RELAXED, AGENT);
}

// ============== p2: verdict + hoisted readout + rare synchronous fallback (R7) ==============
__global__ __launch_bounds__(256, 1) void p2_fallback(
    const __hip_bfloat16* __restrict__ Xh, const __hip_bfloat16* __restrict__ Wxh,
    const float* __restrict__ Wst, const uint64_t* __restrict__ p1f,
    uint64_t* __restrict__ sums, uint64_t* __restrict__ chunks,
    const float* __restrict__ bvec, const float* __restrict__ tau_m, const float* __restrict__ tau_n,
    const float* __restrict__ Wr, const float* __restrict__ brv, const float* __restrict__ tau_r,
    const float* __restrict__ mem0, float* __restrict__ out)
{
    __shared__ __align__(16) char smem[SM_TOTAL];
    __shared__ uint32_t stageW[16];
    __shared__ uint64_t roSnap[16];
    __shared__ unsigned fPollDone[2], fStgw[2], fCorr[2];
    __shared__ unsigned fRoSnap, dirtyH[2];

    __hip_bfloat16* Bp    = (__hip_bfloat16*)(smem + SM_BP);
    uint8_t*        Apre2 = (uint8_t*)(smem + SM_A2);
    float*          curL2 = (float*)(smem + SM_CURL2);
    uint8_t*        mTb   = (uint8_t*)(smem + SM_MTB);

    const int wg   = blockIdx.x;     // 0..255
    const int tid  = threadIdx.x;
    const int lane = tid & 63, wid = tid >> 6;
    const int colA = lane & 15, kb8 = (lane >> 4) * 8;

    if (tid < 2) { fPollDone[tid] = 0; fStgw[tid] = 0; fCorr[tid] = 0; dirtyH[tid] = 0; }
    if (tid == 0) fRoSnap = 0;
    __syncthreads();

    // verdict from p1 flags (stream-ordered: plain loads)
    {
        uint64_t v0 = p1f[tid];
        uint64_t v1 = p1f[tid + 256];
        if ((unsigned)v0) dirtyH[(tid & 7) >> 2] = 1u;          // half of rows = rtile>>2
        if ((unsigned)v1) dirtyH[((tid + 256) & 7) >> 2] = 1u;
    }
    __syncthreads();

    // readout consts (o = lane)
    float r_alpha = 0.f, r_bias = 0.f;
    const float* WrRow = Wr;
    if (wid == 0 && lane < 32) {
        int o = (lane < OUTD) ? lane : 0;
        r_alpha = sigmoidf(tau_r[o]);
        r_bias  = brv[o];
        WrRow   = Wr + o * HID;
    }

    // clean halves: hoisted readout (input-independent under zero spikes), b = wg
    if (wg < BATCH && wid == 0 && lane < 32 && !dirtyH[wg >> 6]) {
        float rr = 0.f, racc = 0.f;
        for (int t = 0; t < T_STEPS; ++t) {
            rr = r_alpha * rr + (1.0f - r_alpha) * r_bias;   // rsum = 0
            float vmax = (lane < OUTD) ? rr : -__builtin_inff();
            #pragma unroll
            for (int d = 16; d > 0; d >>= 1) vmax = fmaxf(vmax, __shfl_xor(vmax, d, 32));
            float e = (lane < OUTD) ? expf(rr - vmax) : 0.f;
            float ss = e;
            #pragma unroll
            for (int d = 16; d > 0; d >>= 1) ss += __shfl_xor(ss, d, 32);
            if (t >= 1) racc += e / ss;   // WARMUP=0
        }
        if (lane < OUTD) out[wg * OUTD + lane] = racc;
    }
    if (!dirtyH[wg >> 7]) return;

    // ---------------- synchronous fallback (verbatim R7, tags +1) ----------------
    float r_rmem = 0.f, r_acc = 0.f;
    const int w2    = wg & 127;
    const int bhalf = wg >> 7;
    const int bbase = bhalf * 64;
    const int c0    = w2 * 32;
    const int i0    = w2 * 8;
    const int roB2  = (wg < 64) ? wg : ((wg >= 128 && wg < 192) ? wg - 64 : -1);

    for (int idx = tid; idx < 32 * 88; idx += WGT) {
        int col = idx / 88, m = idx % 88;
        *(short8*)(Bp + col * 712 + m * 8) = *(const short8*)(Wxh + (long)(c0 + col) * KPAD + m * 8);
    }
    for (int idx = tid; idx < 64 * 136 / 4; idx += WGT)
        ((uint32_t*)mTb)[idx] = 0u;

    const int mwid = wid - 2;
    const int st   = tid - 128;
    const int r2   = st >> 1;
    const int half = st & 1;
    float dn2[16], bt2[16], omb2[16], bias2[16], alph2[4], oma2[4], mem2[4], spk2[4];
    if (wid >= 2) {
        const int b2 = bbase + r2;
        #pragma unroll
        for (int n = 0; n < 4; ++n) {
            int i = i0 + half * 4 + n;
            alph2[n] = sigmoidf(tau_m[i]);
            oma2[n]  = 1.0f - alph2[n];
            mem2[n]  = mem0[b2 * HID + i];
            spk2[n]  = 0.0f;
            #pragma unroll
            for (int j = 0; j < 4; ++j) {
                int idx = n * 4 + j;
                bt2[idx]   = sigmoidf(tau_n[i * 4 + j]);
                omb2[idx]  = 1.0f - bt2[idx];
                bias2[idx] = bvec[i * 4 + j];
                dn2[idx]   = 0.0f;
            }
        }
    }
    const int trRow = mwid * 32;
    const int rb2   = trRow + (lane & 15);
    const int sw2   = rb2 & 7;
    uint8_t* dst2   = Apre2 + mwid * 45056;

    if (wid >= 2) {
        const char* gsrc = (const char*)Xh + ((size_t)bhalf * UPB) * 16 + (size_t)mwid * 45056;
        #pragma unroll
        for (int i = 0; i < 44; ++i)
            dma16(gsrc + i * 1024 + lane * 16, dst2 + i * 1024);
    }
    asm volatile("s_waitcnt vmcnt(0)" ::: "memory");
    __syncthreads();

    if (wid < 2) {
        // ---- poll waves ----
        const int plane = tid;
        for (int k = 1; k <= T_STEPS; ++k) {
            const size_t base = ((size_t)((k - 1) & 1) * 2 + bhalf) * 128 + plane;
            const unsigned want = (unsigned)(k + 1);
            uint64_t v;
            for (;;) {
                v = __hip_atomic_load(sums + base, __ATOMIC_RELAXED, AGENT);
                if ((unsigned)(v >> 32) == want) break;
                __builtin_amdgcn_s_sleep(1);
            }
            unsigned mysum = (unsigned)v;
            if (mysum) {
                if (wid == 1)
                    while (ldsLd(&fRoSnap) < (unsigned)(k - 1)) {}
                const uint64_t* rec = chunks + base * 16;
                uint8_t* col = mTb + plane;
                unsigned pend = mysum;
                while (pend) {
                    int c = __builtin_ctz(pend);
                    uint64_t cv = __hip_atomic_load(rec + c, __ATOMIC_RELAXED, AGENT);
                    if ((unsigned)(cv >> 32) == want) {
                        pend &= pend - 1;
                        unsigned pay = (unsigned)cv;
                        col[(4 * c + 0) * 136] = (uint8_t)(pay);
                        col[(4 * c + 1) * 136] = (uint8_t)(pay >> 8);
                        col[(4 * c + 2) * 136] = (uint8_t)(pay >> 16);
                        col[(4 * c + 3) * 136] = (uint8_t)(pay >> 24);
                    } else {
                        __builtin_amdgcn_s_sleep(1);
                    }
                }
            }
            const bool anyW = __any(mysum != 0u);
            if (lane == 0)
                ldsSt(&fPollDone[wid], ((unsigned)k << 1) | (anyW ? 1u : 0u));

            if (wid == 0) {
                while ((ldsLd(&fPollDone[1]) >> 1) < (unsigned)k) {}
                if (roB2 >= 0 && lane < 16)
                    roSnap[lane] = ((const uint64_t*)(mTb + (roB2 & 63) * 136))[lane];
                asm volatile("s_waitcnt lgkmcnt(0)" ::: "memory");
                if (lane == 0) ldsSt(&fRoSnap, (unsigned)k);
                if (roB2 >= 0 && lane < 32) {
                    float rsum = 0.f;
                    #pragma unroll 4
                    for (int q = 0; q < 16; ++q) {
                        uint64_t mword = roSnap[q];
                        while (mword) {
                            int h = (q << 6) + __builtin_ctzll(mword);
                            mword &= mword - 1;
                            rsum += WrRow[h];
                        }
                    }
                    r_rmem = r_alpha * r_rmem + (1.0f - r_alpha) * (rsum + r_bias);
                    float vmax = (lane < OUTD) ? r_rmem : -__builtin_inff();
                    #pragma unroll
                    for (int d = 16; d > 0; d >>= 1) vmax = fmaxf(vmax, __shfl_xor(vmax, d, 32));
                    float e = (lane < OUTD) ? expf(r_rmem - vmax) : 0.f;
                    float ssum = e;
                    #pragma unroll
                    for (int d = 16; d > 0; d >>= 1) ssum += __shfl_xor(ssum, d, 32);
                    if (k >= 2) r_acc += e / ssum;
                }
            }
        }
        if (wid == 0 && roB2 >= 0 && lane < OUTD) out[roB2 * OUTD + lane] = r_acc;
    } else {
        // ---- compute waves ----
        const float* clp = curL2 + r2 * 36 + half * 16;
        for (int t = 0; t < T_STEPS; ++t) {
            f32x4 a00 = {0,0,0,0}, a01 = {0,0,0,0}, a10 = {0,0,0,0}, a11 = {0,0,0,0};
            #pragma unroll
            for (int k0 = 0; k0 < KPAD; k0 += 32) {
                int k8 = (k0 >> 3) + (lane >> 4);
                short8 f0 = *(const short8*)&Apre2[(((rb2)      * 88 + (k8 ^ sw2)) << 4)];
                short8 f1 = *(const short8*)&Apre2[(((rb2 + 16) * 88 + (k8 ^ sw2)) << 4)];
                short8 b0 = *(const short8*)(&Bp[(colA) * 712 + k0 + kb8]);
                short8 b1 = *(const short8*)(&Bp[(16 + colA) * 712 + k0 + kb8]);
                a00 = __builtin_amdgcn_mfma_f32_16x16x32_bf16(f0, b0, a00, 0, 0, 0);
                a01 = __builtin_amdgcn_mfma_f32_16x16x32_bf16(f0, b1, a01, 0, 0, 0);
                a10 = __builtin_amdgcn_mfma_f32_16x16x32_bf16(f1, b0, a10, 0, 0, 0);
                a11 = __builtin_amdgcn_mfma_f32_16x16x32_bf16(f1, b1, a11, 0, 0, 0);
            }
            asm volatile("s_waitcnt lgkmcnt(0)" ::: "memory");
            __builtin_amdgcn_sched_barrier(0);
            if (t + 1 < T_STEPS) {
                const char* gsrc = (const char*)Xh
                    + (((size_t)(t + 1) * 2 + bhalf) * UPB) * 16 + (size_t)mwid * 45056;
                #pragma unroll
                for (int i = 0; i < 44; ++i)
                    dma16(gsrc + i * 1024 + lane * 16, dst2 + i * 1024);
            }
            {
                const int crow0 = trRow + ((lane >> 4) << 2);
                #pragma unroll
                for (int j = 0; j < 4; ++j) {
                    curL2[(crow0 + j) * 36 + colA]           = a00[j];
                    curL2[(crow0 + j) * 36 + 16 + colA]      = a01[j];
                    curL2[(crow0 + 16 + j) * 36 + colA]      = a10[j];
                    curL2[(crow0 + 16 + j) * 36 + 16 + colA] = a11[j];
                }
            }
            asm volatile("s_waitcnt lgkmcnt(0)" ::: "memory");
            __builtin_amdgcn_sched_barrier(0);

            f32x4 cv0 = *(const f32x4*)(clp + 0);
            f32x4 cv1 = *(const f32x4*)(clp + 4);
            f32x4 cv2 = *(const f32x4*)(clp + 8);
            f32x4 cv3 = *(const f32x4*)(clp + 12);
            float cl[16];
            #pragma unroll
            for (int e = 0; e < 4; ++e) {
                cl[e] = cv0[e]; cl[4 + e] = cv1[e]; cl[8 + e] = cv2[e]; cl[12 + e] = cv3[e];
            }
            float memS[4], spkS[4];
            #pragma unroll
            for (int n = 0; n < 4; ++n) {
                float lin = 0.f;
                #pragma unroll
                for (int j = 0; j < 4; ++j) {
                    int idx = n * 4 + j;
                    dn2[idx] = bt2[idx] * dn2[idx] + omb2[idx] * (cl[idx] + bias2[idx]);
                    lin += dn2[idx];
                }
                memS[n] = alph2[n] * mem2[n] + oma2[n] * lin - spk2[n];
                spkS[n] = (memS[n] > 1.0f) ? 1.0f : 0.0f;
            }
            unsigned nib = 0;
            #pragma unroll
            for (int n = 0; n < 4; ++n) nib |= (spkS[n] != 0.f ? 1u : 0u) << (half * 4 + n);
            nib |= (unsigned)__shfl_xor((int)nib, 1);
            if (half == 0) ((uint8_t*)stageW)[r2] = (uint8_t)nib;
            if (lane == 0) ldsSt(&fStgw[mwid], (unsigned)(t + 1));

            bool anySpk = false;
            if (t > 0) {
                unsigned p0, p1;
                do { p0 = ldsLd(&fPollDone[0]); } while ((p0 >> 1) < (unsigned)t);
                do { p1 = ldsLd(&fPollDone[1]); } while ((p1 >> 1) < (unsigned)t);
                anySpk = ((p0 | p1) & 1u) != 0u;
            }
            if (anySpk) {
                float recv[16];
                #pragma unroll
                for (int e = 0; e < 16; ++e) recv[e] = 0.f;
                const float* Wb = Wst + c0 + half * 16;
                const uint64_t* mrow = (const uint64_t*)(mTb + r2 * 136);
                for (int q = 0; q < 16; ++q) {
                    uint64_t mword = mrow[q];
                    while (mword) {
                        int h = (q << 6) + __builtin_ctzll(mword);
                        mword &= mword - 1;
                        const f32x4* wv = (const f32x4*)(Wb + (long)h * NCOL);
                        f32x4 w0 = wv[0], w1 = wv[1], w2v = wv[2], w3 = wv[3];
                        #pragma unroll
                        for (int e = 0; e < 4; ++e) {
                            recv[e] += w0[e]; recv[4 + e] += w1[e];
                            recv[8 + e] += w2v[e]; recv[12 + e] += w3[e];
                        }
                    }
                }
                #pragma unroll
                for (int n = 0; n < 4; ++n) {
                    float cs = 0.f;
                    #pragma unroll
                    for (int j = 0; j < 4; ++j) {
                        int idx = n * 4 + j;
                        float ad = omb2[idx] * recv[idx];
                        dn2[idx] += ad; cs += ad;
                    }
                    memS[n] += oma2[n] * cs;
                    spkS[n] = (memS[n] > 1.0f) ? 1.0f : 0.0f;
                }
                unsigned nib2 = 0;
                #pragma unroll
                for (int n = 0; n < 4; ++n) nib2 |= (spkS[n] != 0.f ? 1u : 0u) << (half * 4 + n);
                nib2 |= (unsigned)__shfl_xor((int)nib2, 1);
                if (half == 0) ((uint8_t*)stageW)[r2] = (uint8_t)nib2;
                if (roB2 >= 0) while (ldsLd(&fRoSnap) < (unsigned)t) {}
                uint64_t* mz = (uint64_t*)(mTb + r2 * 136) + half * 8;
                #pragma unroll
                for (int e = 0; e < 8; ++e) mz[e] = 0;
                if (lane == 0) ldsSt(&fCorr[mwid], (unsigned)(t + 1));
            }
            #pragma unroll
            for (int n = 0; n < 4; ++n) { mem2[n] = memS[n]; spk2[n] = spkS[n]; }

            if (mwid == 0) {
                while (ldsLd(&fStgw[1]) < (unsigned)(t + 1)) {}
                if (anySpk) while (ldsLd(&fCorr[1]) < (unsigned)(t + 1)) {}
                unsigned pay = (lane < 16) ? stageW[lane] : 0u;
                const size_t pbase = ((size_t)(t & 1) * 2 + bhalf) * 128 + w2;
                if (lane < 16 && pay)
                    __hip_atomic_store(chunks + pbase * 16 + lane,
                                       ((uint64_t)(unsigned)(t + 2) << 32) | (uint64_t)pay,
                                       __ATOMIC_RELAXED, AGENT);
                uint64_t bal = __ballot(pay != 0u);
                if (lane == 0)
                    __hip_atomic_store(sums + pbase,
                                       ((uint64_t)(unsigned)(t + 2) << 32) | (uint64_t)(bal & 0xFFFFull),
                                       __ATOMIC_RELAXED, AGENT);
            }
            asm volatile("s_waitcnt vmcnt(0)" ::: "memory");
        }
    }
}

extern "C" void kernel_launch(void* const* d_in, const int* in_sizes, int n_in,
                              void* d_out, int out_size, void* d_ws, size_t ws_size,
                              hipStream_t stream) {
    (void)in_sizes; (void)n_in; (void)out_size; (void)ws_size;
    const float* x     = (const float*)d_in[0];
    const float* W     = (const float*)d_in[1];
    const float* bv    = (const float*)d_in[2];
    const float* tau_m = (const float*)d_in[3];
    const float* tau_n = (const float*)d_in[4];
    const float* Wr    = (const float*)d_in[5];
    const float* br    = (const float*)d_in[6];
    const float* tau_r = (const float*)d_in[7];
    const float* mem0  = (const float*)d_in[8];

    char* ws = (char*)d_ws;
    uint64_t*        p1flag = (uint64_t*)(ws + O_P1F);
    uint64_t*        sums   = (uint64_t*)(ws + O_SUM);
    uint64_t*        chunks = (uint64_t*)(ws + O_CHK);
    float*           Wst    = (float*)(ws + O_WST);
    __hip_bfloat16*  Wxh    = (__hip_bfloat16*)(ws + O_WXH);
    __hip_bfloat16*  Xh     = (__hip_bfloat16*)(ws + O_XH);

    prep_x<<<2048, 256, 0, stream>>>(x, Xh);
    prep_w<<<2048, 256, 0, stream>>>(W, Wxh, p1flag, sums, chunks);
    dim3 g3(32, 128), b3(32, 8);
    prep_t<<<g3, b3, 0, stream>>>(W, Wst);
    p1_scan<<<512, WGT, 0, stream>>>(Xh, Wxh, bv, tau_m, tau_n, mem0, p1flag);
    p2_fallback<<<256, WGT, 0, stream>>>(Xh, Wxh, Wst, p1flag, sums, chunks,
                                         bv, tau_m, tau_n, Wr, br, tau_r, mem0, (float*)d_out);
}

// Round 14
// 385.025 us; speedup vs baseline: 1.4564x; 1.1742x over previous
//
#include <hip/hip_runtime.h>
#include <hip/hip_bf16.h>
#include <stdint.h>

// DH-SNN forward: two-phase optimistic execution, v5.
// prep_all (fused): x->Xh swizzled bf16 | W->Wxh bf16 + zero exchange | W^T->Wst, one kernel.
// p1_scan (512 WGs, 2/CU): zero-spike free-run, WG = 16 rows (rtile=wg&7==XCD) x 64 cols.
//   - update(t-1) software-pipelined INTO the MFMA(t) basic block (VALU overlaps MFMA/LDS).
//   - parity exchange buffer -> ONE barrier per step; 2-buffer A prefetch (1-ahead).
//   - B = 22 frags = 88 VGPR resident; LDS 61.4KB -> 2 WGs/CU.
// p2_fallback: verdict + hoisted input-independent readout; rare dirty half runs verbatim R7.

typedef short short8 __attribute__((ext_vector_type(8)));
typedef float f32x4 __attribute__((ext_vector_type(4)));

#define T_STEPS 250
#define BATCH   128
#define HID     1024
#define NCOL    4096
#define IND     700
#define ISZ     1724
#define KPAD    704
#define OUTD    20
#define WGT     256
#define UPB     5632      // 16B units per (t,half64) A block

// ws layout (bytes)
#define O_P1F   0                // u64[512] phase-1 flags
#define O_SUM   4096             // u64[2 parity][2 half][128 wg]
#define O_CHK   8192             // u64[2][2][128][16]
#define O_WST   73728            // f32 [1024][4096]
#define O_WXH   16850944         // bf16 [4096][704]
#define O_XH    22618112         // bf16 [250][2][5632][8] swizzled

// p2 smem arena
#define SM_BP    0
#define SM_A2    45568
#define SM_CURL2 135680
#define SM_MTB   144896
#define SM_TOTAL 153600

#define AGENT __HIP_MEMORY_SCOPE_AGENT

__device__ __forceinline__ float sigmoidf(float x) { return 1.0f / (1.0f + expf(-x)); }

__device__ __forceinline__ unsigned ldsLd(const unsigned* p) {
    return __hip_atomic_load(p, __ATOMIC_ACQUIRE, __HIP_MEMORY_SCOPE_WORKGROUP);
}
__device__ __forceinline__ void ldsSt(unsigned* p, unsigned v) {
    __hip_atomic_store(p, v, __ATOMIC_RELEASE, __HIP_MEMORY_SCOPE_WORKGROUP);
}

__device__ __forceinline__ void dma16(const void* g, void* l) {
    __builtin_amdgcn_global_load_lds(
        (const __attribute__((address_space(1))) unsigned int*)g,
        (__attribute__((address_space(3))) unsigned int*)l, 16, 0, 0);
}

// quad-lane sum (lanes xor 1, xor 2) via DPP quad_perm — pure VALU
__device__ __forceinline__ float qsum4(float v) {
    union { float f; int i; } a, b;
    a.f = v; b.i = __builtin_amdgcn_mov_dpp(a.i, 0xB1, 0xF, 0xF, true); v += b.f;  // xor 1
    a.f = v; b.i = __builtin_amdgcn_mov_dpp(a.i, 0x4E, 0xF, 0xF, true); v += b.f;  // xor 2
    return v;
}

__device__ __forceinline__ short bf16bits(float v) {
    union { __hip_bfloat16 h; short s; } u;
    u.h = __float2bfloat16(v);
    return u.s;
}

// ================= fused prep: x-swizzle | W->bf16 + zero flags | W^T =================
__global__ __launch_bounds__(256) void prep_all(
    const float* __restrict__ x, const float* __restrict__ W,
    __hip_bfloat16* __restrict__ Xh, __hip_bfloat16* __restrict__ Wxh,
    float* __restrict__ Wst, uint64_t* __restrict__ p1f,
    uint64_t* __restrict__ sums, uint64_t* __restrict__ chunks)
{
    const int bid = blockIdx.x;
    const int tid = threadIdx.x;

    if (bid < 2048) {
        // x -> Xh, pre-swizzled: unit q of block (t,half64) = (row=q/88, k=((q%88)^(row&7))*8+e)
        const int total = T_STEPS * 2 * UPB;
        for (int unit = bid * 256 + tid; unit < total; unit += 2048 * 256) {
            int q    = unit % UPB;
            int blk  = unit / UPB;
            int half = blk & 1, t = blk >> 1;
            int row  = q / 88, m = q % 88;
            int k8   = m ^ (row & 7);
            int b    = half * 64 + row;
            int k0   = k8 * 8;
            const float* xp = x + ((long)b * T_STEPS + t) * IND + k0;
            short8 o;
            if (k0 + 8 <= IND) {
                f32x4 v0 = *(const f32x4*)xp;
                f32x4 v1 = *(const f32x4*)(xp + 4);
                #pragma unroll
                for (int e = 0; e < 4; ++e) { o[e] = bf16bits(v0[e]); o[4 + e] = bf16bits(v1[e]); }
            } else {
                #pragma unroll
                for (int e = 0; e < 8; ++e)
                    o[e] = bf16bits((k0 + e < IND) ? xp[e] : 0.0f);
            }
            *(short8*)(Xh + (size_t)unit * 8) = o;
        }
    } else if (bid < 4096) {
        if (bid == 2048) {   // zero exchange area every launch (graph replay + 0xAA poison)
            for (int i = tid; i < 512; i += 256)
                __hip_atomic_store(&p1f[i], 0ull, __ATOMIC_RELAXED, AGENT);
            for (int i = tid; i < 2 * 2 * 128; i += 256)
                __hip_atomic_store(&sums[i], 0ull, __ATOMIC_RELAXED, AGENT);
            for (int i = tid; i < 2 * 2 * 128 * 16; i += 256)
                __hip_atomic_store(&chunks[i], 0ull, __ATOMIC_RELAXED, AGENT);
        }
        const int total = NCOL * 88;
        for (int unit = (bid - 2048) * 256 + tid; unit < total; unit += 2048 * 256) {
            int n = unit / 88, m = unit % 88;
            int k0 = m * 8;
            const float* wp = W + (long)n * ISZ + k0;
            short8 o;
            if (k0 + 8 <= IND) {
                f32x4 v0 = *(const f32x4*)wp;
                f32x4 v1 = *(const f32x4*)(wp + 4);
                #pragma unroll
                for (int e = 0; e < 4; ++e) { o[e] = bf16bits(v0[e]); o[4 + e] = bf16bits(v1[e]); }
            } else {
                #pragma unroll
                for (int e = 0; e < 8; ++e)
                    o[e] = bf16bits((k0 + e < IND) ? wp[e] : 0.0f);
            }
            *(short8*)(Wxh + (long)n * KPAD + k0) = o;
        }
    } else {
        // Wst[h][n] = W[n][700+h]  (tiled transpose; tile idx = bid-4096: hx=idx&31, ny=idx>>5)
        __shared__ float tile[32][33];
        const int idx = bid - 4096;
        const int h0 = (idx & 31) * 32, n0 = (idx >> 5) * 32;
        const int tx = tid & 31, ty = tid >> 5;   // (32,8)
        #pragma unroll
        for (int j = 0; j < 32; j += 8)
            tile[ty + j][tx] = W[(long)(n0 + ty + j) * ISZ + IND + h0 + tx];
        __syncthreads();
        #pragma unroll
        for (int j = 0; j < 32; j += 8)
            Wst[(long)(h0 + ty + j) * NCOL + n0 + tx] = tile[tx][ty + j];
    }
}

// ======================= p1: pipelined optimistic free-run (512 WGs, 2/CU) =======================
__global__ __launch_bounds__(256, 2) void p1_scan(
    const __hip_bfloat16* __restrict__ Xh, const __hip_bfloat16* __restrict__ Wxh,
    const float* __restrict__ bvec, const float* __restrict__ tau_m,
    const float* __restrict__ tau_n, const float* __restrict__ mem0,
    uint64_t* __restrict__ p1f)
{
    __shared__ __align__(16) uint8_t Abuf[2][22528];    // 45056 B double-buffered A slice
    __shared__ __align__(16) float preg[2][8 * 256];    // 16384 B parity exchange
    __shared__ unsigned anySpkF;

    const int wg    = blockIdx.x;        // 0..511
    const int rtile = wg & 7;            // batch rows [rtile*16,+16)  (== XCD round-robin)
    const int ctile = wg >> 3;           // cols [ctile*64,+64)
    const int tid   = threadIdx.x;
    const int lane  = tid & 63, wid = tid >> 6;
    const int colA  = lane & 15, kb8 = (lane >> 4) * 8;
    const int cg    = wid >> 1;          // col half
    const int p     = wid & 1;           // k half: chunks [11p, 11p+11)

    if (tid == 0) anySpkF = 0u;

    // per-lane state (MFMA C-layout): 2 cols x 4 rows
    const int colG0 = ctile * 64 + cg * 32 + colA;
    const int colG1 = colG0 + 16;
    const int rowB  = rtile * 16 + (lane >> 4) * 4;
    float bt_[2], omb_[2], bias_[2], al_[2], oma_[2], dn[2][4], mem_[2][4];
    {
        const int cG[2] = {colG0, colG1};
        #pragma unroll
        for (int i = 0; i < 2; ++i) {
            bt_[i]   = sigmoidf(tau_n[cG[i]]);
            omb_[i]  = 1.0f - bt_[i];
            bias_[i] = bvec[cG[i]];
            al_[i]   = sigmoidf(tau_m[cG[i] >> 2]);
            oma_[i]  = 1.0f - al_[i];
            #pragma unroll
            for (int j = 0; j < 4; ++j) {
                dn[i][j]   = 0.0f;
                mem_[i][j] = mem0[(rowB + j) * HID + (cG[i] >> 2)];
            }
        }
    }

    // B panel -> registers: 22 frags = 88 VGPR
    short8 Breg[22];
    #pragma unroll
    for (int j = 0; j < 11; ++j) {
        Breg[2 * j]     = *(const short8*)(Wxh + (long)colG0 * KPAD + (11 * p + j) * 32 + kb8);
        Breg[2 * j + 1] = *(const short8*)(Wxh + (long)colG1 * KPAD + (11 * p + j) * 32 + kb8);
    }
    asm volatile("s_waitcnt vmcnt(0)" ::: "memory");
    __builtin_amdgcn_sched_barrier(0);
    #pragma unroll
    for (int i = 0; i < 22; ++i) asm volatile("" : "+v"(Breg[i]));

    // A DMA plan: 22 x 1KB units per slice; waves 0,1 -> 6 units, waves 2,3 -> 5
    const size_t sliceBase = (size_t)(rtile >> 2) * 90112 + (size_t)(rtile & 3) * 22528;
    const int dstart = (wid < 2) ? wid * 6 : 12 + (wid - 2) * 5;
    const int dcnt   = (wid < 2) ? 6 : 5;
    const char* XhB  = (const char*)Xh;

    #define ISSUE_A(T, BUF)                                                            \
        do {                                                                           \
            const char* _g = XhB + sliceBase + (size_t)(T) * 180224;                   \
            _Pragma("unroll")                                                          \
            for (int _i = 0; _i < 6; ++_i)                                             \
                if (_i < dcnt)                                                         \
                    dma16(_g + (size_t)(dstart + _i) * 1024 + (size_t)lane * 16,       \
                          (BUF) + (dstart + _i) * 1024);                               \
        } while (0)

    const int rl = lane & 15;
    const int sw = rl & 7;

    #define MFMA_BLOCK(AB, A0, A1)                                                             \
        do {                                                                                   \
            _Pragma("unroll")                                                                  \
            for (int _j = 0; _j < 11; ++_j) {                                                  \
                int _k8 = (11 * p + _j) * 4 + (lane >> 4);                                     \
                short8 _a = *(const short8*)((AB) + ((rl * 88 + (_k8 ^ sw)) << 4));            \
                A0 = __builtin_amdgcn_mfma_f32_16x16x32_bf16(_a, Breg[2 * _j],     A0, 0,0,0); \
                A1 = __builtin_amdgcn_mfma_f32_16x16x32_bf16(_a, Breg[2 * _j + 1], A1, 0,0,0); \
            }                                                                                  \
        } while (0)

    #define UPDATE_STEP(CS0, CS1)                                                  \
        do {                                                                       \
            _Pragma("unroll")                                                      \
            for (int _j = 0; _j < 4; ++_j) {                                       \
                float _d0 = bt_[0] * dn[0][_j] + omb_[0] * ((CS0)[_j] + bias_[0]); \
                float _d1 = bt_[1] * dn[1][_j] + omb_[1] * ((CS1)[_j] + bias_[1]); \
                dn[0][_j] = _d0; dn[1][_j] = _d1;                                  \
                float _l0 = qsum4(_d0), _l1 = qsum4(_d1);                          \
                float _m0 = al_[0] * mem_[0][_j] + oma_[0] * _l0;                  \
                float _m1 = al_[1] * mem_[1][_j] + oma_[1] * _l1;                  \
                mem_[0][_j] = _m0; mem_[1][_j] = _m1;                              \
                memmax = fmaxf(memmax, fmaxf(_m0, _m1));                           \
            }                                                                      \
        } while (0)

    float memmax = -1e30f;
    f32x4 own0, own1, prt0, prt1;
    const int wrSlot = (cg * 2 + (1 - p)) * 2;
    const int rdSlot = (cg * 2 + p) * 2;

    // prologue: DMA A[0]
    ISSUE_A(0, Abuf[0]);
    asm volatile("s_waitcnt vmcnt(0)" ::: "memory");
    __builtin_amdgcn_sched_barrier(0);
    __syncthreads();

    // peeled t = 0 (no update)
    {
        ISSUE_A(1, Abuf[1]);
        f32x4 acc0 = {0,0,0,0}, acc1 = {0,0,0,0};
        MFMA_BLOCK(Abuf[0], acc0, acc1);
        float* wq = &preg[0][wrSlot * 256 + lane * 4];
        *(f32x4*)wq = acc0; *(f32x4*)(wq + 256) = acc1;
        asm volatile("s_waitcnt vmcnt(0) lgkmcnt(0)" ::: "memory");
        __builtin_amdgcn_sched_barrier(0);
        __builtin_amdgcn_s_barrier();
        const float* rq = &preg[0][rdSlot * 256 + lane * 4];
        prt0 = *(const f32x4*)rq; prt1 = *(const f32x4*)(rq + 256);
        own0 = acc0; own1 = acc1;
    }

    // main loop: MFMA(t) with update(t-1) in the same block (VALU overlaps MFMA/LDS)
    for (int t = 1; t < T_STEPS; ++t) {
        if (t + 1 < T_STEPS)
            ISSUE_A(t + 1, Abuf[(t + 1) & 1]);
        f32x4 acc0 = {0,0,0,0}, acc1 = {0,0,0,0};
        MFMA_BLOCK(Abuf[t & 1], acc0, acc1);
        {
            f32x4 cs0 = own0 + prt0;
            f32x4 cs1 = own1 + prt1;
            UPDATE_STEP(cs0, cs1);
        }
        float* wq = &preg[t & 1][wrSlot * 256 + lane * 4];
        *(f32x4*)wq = acc0; *(f32x4*)(wq + 256) = acc1;
        asm volatile("s_waitcnt vmcnt(0) lgkmcnt(0)" ::: "memory");
        __builtin_amdgcn_sched_barrier(0);
        __builtin_amdgcn_s_barrier();
        const float* rq = &preg[t & 1][rdSlot * 256 + lane * 4];
        prt0 = *(const f32x4*)rq; prt1 = *(const f32x4*)(rq + 256);
        own0 = acc0; own1 = acc1;
    }

    // epilogue: update for t = T_STEPS-1
    {
        f32x4 cs0 = own0 + prt0;
        f32x4 cs1 = own1 + prt1;
        UPDATE_STEP(cs0, cs1);
    }

    if (__any(memmax > 1.0f) && lane == 0) anySpkF = 1u;
    __syncthreads();
    if (tid == 0)
        __hip_atomic_store(p1f + wg, (1ull << 32) | (uint64_t)anySpkF,
                           __ATOMIC_RELAXED, AGENT);
    #undef ISSUE_A
    #undef MFMA_BLOCK
    #undef UPDATE_STEP
}

// ============== p2: verdict + hoisted readout + rare synchronous fallback (R7) ==============
__global__ __launch_bounds__(256, 1) void p2_fallback(
    const __hip_bfloat16* __restrict__ Xh, const __hip_bfloat16* __restrict__ Wxh,
    const float* __restrict__ Wst, const uint64_t* __restrict__ p1f,
    uint64_t* __restrict__ sums, uint64_t* __restrict__ chunks,
    const float* __restrict__ bvec, const float* __restrict__ tau_m, const float* __restrict__ tau_n,
    const float* __restrict__ Wr, const float* __restrict__ brv, const float* __restrict__ tau_r,
    const float* __restrict__ mem0, float* __restrict__ out)
{
    __shared__ __align__(16) char smem[SM_TOTAL];
    __shared__ uint32_t stageW[16];
    __shared__ uint64_t roSnap[16];
    __shared__ unsigned fPollDone[2], fStgw[2], fCorr[2];
    __shared__ unsigned fRoSnap, dirtyH[2];

    __hip_bfloat16* Bp    = (__hip_bfloat16*)(smem + SM_BP);
    uint8_t*        Apre2 = (uint8_t*)(smem + SM_A2);
    float*          curL2 = (float*)(smem + SM_CURL2);
    uint8_t*        mTb   = (uint8_t*)(smem + SM_MTB);

    const int wg   = blockIdx.x;     // 0..255
    const int tid  = threadIdx.x;
    const int lane = tid & 63, wid = tid >> 6;
    const int colA = lane & 15, kb8 = (lane >> 4) * 8;

    if (tid < 2) { fPollDone[tid] = 0; fStgw[tid] = 0; fCorr[tid] = 0; dirtyH[tid] = 0; }
    if (tid == 0) fRoSnap = 0;
    __syncthreads();

    // verdict from p1 flags (stream-ordered: plain loads)
    {
        uint64_t v0 = p1f[tid];
        uint64_t v1 = p1f[tid + 256];
        if ((unsigned)v0) dirtyH[(tid & 7) >> 2] = 1u;
        if ((unsigned)v1) dirtyH[((tid + 256) & 7) >> 2] = 1u;
    }
    __syncthreads();

    float r_alpha = 0.f, r_bias = 0.f;
    const float* WrRow = Wr;
    if (wid == 0 && lane < 32) {
        int o = (lane < OUTD) ? lane : 0;
        r_alpha = sigmoidf(tau_r[o]);
        r_bias  = brv[o];
        WrRow   = Wr + o * HID;
    }

    // clean halves: hoisted readout (input-independent under zero spikes), b = wg
    if (wg < BATCH && wid == 0 && lane < 32 && !dirtyH[wg >> 6]) {
        float rr = 0.f, racc = 0.f;
        for (int t = 0; t < T_STEPS; ++t) {
            rr = r_alpha * rr + (1.0f - r_alpha) * r_bias;
            float vmax = (lane < OUTD) ? rr : -__builtin_inff();
            #pragma unroll
            for (int d = 16; d > 0; d >>= 1) vmax = fmaxf(vmax, __shfl_xor(vmax, d, 32));
            float e = (lane < OUTD) ? expf(rr - vmax) : 0.f;
            float ss = e;
            #pragma unroll
            for (int d = 16; d > 0; d >>= 1) ss += __shfl_xor(ss, d, 32);
            if (t >= 1) racc += e / ss;
        }
        if (lane < OUTD) out[wg * OUTD + lane] = racc;
    }
    if (!dirtyH[wg >> 7]) return;

    // ---------------- synchronous fallback (verbatim R7, tags +1) ----------------
    float r_rmem = 0.f, r_acc = 0.f;
    const int w2    = wg & 127;
    const int bhalf = wg >> 7;
    const int bbase = bhalf * 64;
    const int c0    = w2 * 32;
    const int i0    = w2 * 8;
    const int roB2  = (wg < 64) ? wg : ((wg >= 128 && wg < 192) ? wg - 64 : -1);

    for (int idx = tid; idx < 32 * 88; idx += WGT) {
        int col = idx / 88, m = idx % 88;
        *(short8*)(Bp + col * 712 + m * 8) = *(const short8*)(Wxh + (long)(c0 + col) * KPAD + m * 8);
    }
    for (int idx = tid; idx < 64 * 136 / 4; idx += WGT)
        ((uint32_t*)mTb)[idx] = 0u;

    const int mwid = wid - 2;
    const int st   = tid - 128;
    const int r2   = st >> 1;
    const int half = st & 1;
    float dn2[16], bt2[16], omb2[16], bias2[16], alph2[4], oma2[4], mem2[4], spk2[4];
    if (wid >= 2) {
        const int b2 = bbase + r2;
        #pragma unroll
        for (int n = 0; n < 4; ++n) {
            int i = i0 + half * 4 + n;
            alph2[n] = sigmoidf(tau_m[i]);
            oma2[n]  = 1.0f - alph2[n];
            mem2[n]  = mem0[b2 * HID + i];
            spk2[n]  = 0.0f;
            #pragma unroll
            for (int j = 0; j < 4; ++j) {
                int idx = n * 4 + j;
                bt2[idx]   = sigmoidf(tau_n[i * 4 + j]);
                omb2[idx]  = 1.0f - bt2[idx];
                bias2[idx] = bvec[i * 4 + j];
                dn2[idx]   = 0.0f;
            }
        }
    }
    const int trRow = mwid * 32;
    const int rb2   = trRow + (lane & 15);
    const int sw2   = rb2 & 7;
    uint8_t* dst2   = Apre2 + mwid * 45056;

    if (wid >= 2) {
        const char* gsrc = (const char*)Xh + ((size_t)bhalf * UPB) * 16 + (size_t)mwid * 45056;
        #pragma unroll
        for (int i = 0; i < 44; ++i)
            dma16(gsrc + i * 1024 + lane * 16, dst2 + i * 1024);
    }
    asm volatile("s_waitcnt vmcnt(0)" ::: "memory");
    __syncthreads();

    if (wid < 2) {
        // ---- poll waves ----
        const int plane = tid;
        for (int k = 1; k <= T_STEPS; ++k) {
            const size_t base = ((size_t)((k - 1) & 1) * 2 + bhalf) * 128 + plane;
            const unsigned want = (unsigned)(k + 1);
            uint64_t v;
            for (;;) {
                v = __hip_atomic_load(sums + base, __ATOMIC_RELAXED, AGENT);
                if ((unsigned)(v >> 32) == want) break;
                __builtin_amdgcn_s_sleep(1);
            }
            unsigned mysum = (unsigned)v;
            if (mysum) {
                if (wid == 1)
                    while (ldsLd(&fRoSnap) < (unsigned)(k - 1)) {}
                const uint64_t* rec = chunks + base * 16;
                uint8_t* col = mTb + plane;
                unsigned pend = mysum;
                while (pend) {
                    int c = __builtin_ctz(pend);
                    uint64_t cv = __hip_atomic_load(rec + c, __ATOMIC_RELAXED, AGENT);
                    if ((unsigned)(cv >> 32) == want) {
                        pend &= pend - 1;
                        unsigned pay = (unsigned)cv;
                        col[(4 * c + 0) * 136] = (uint8_t)(pay);
                        col[(4 * c + 1) * 136] = (uint8_t)(pay >> 8);
                        col[(4 * c + 2) * 136] = (uint8_t)(pay >> 16);
                        col[(4 * c + 3) * 136] = (uint8_t)(pay >> 24);
                    } else {
                        __builtin_amdgcn_s_sleep(1);
                    }
                }
            }
            const bool anyW = __any(mysum != 0u);
            if (lane == 0)
                ldsSt(&fPollDone[wid], ((unsigned)k << 1) | (anyW ? 1u : 0u));

            if (wid == 0) {
                while ((ldsLd(&fPollDone[1]) >> 1) < (unsigned)k) {}
                if (roB2 >= 0 && lane < 16)
                    roSnap[lane] = ((const uint64_t*)(mTb + (roB2 & 63) * 136))[lane];
                asm volatile("s_waitcnt lgkmcnt(0)" ::: "memory");
                if (lane == 0) ldsSt(&fRoSnap, (unsigned)k);
                if (roB2 >= 0 && lane < 32) {
                    float rsum = 0.f;
                    #pragma unroll 4
                    for (int q = 0; q < 16; ++q) {
                        uint64_t mword = roSnap[q];
                        while (mword) {
                            int h = (q << 6) + __builtin_ctzll(mword);
                            mword &= mword - 1;
                            rsum += WrRow[h];
                        }
                    }
                    r_rmem = r_alpha * r_rmem + (1.0f - r_alpha) * (rsum + r_bias);
                    float vmax = (lane < OUTD) ? r_rmem : -__builtin_inff();
                    #pragma unroll
                    for (int d = 16; d > 0; d >>= 1) vmax = fmaxf(vmax, __shfl_xor(vmax, d, 32));
                    float e = (lane < OUTD) ? expf(r_rmem - vmax) : 0.f;
                    float ssum = e;
                    #pragma unroll
                    for (int d = 16; d > 0; d >>= 1) ssum += __shfl_xor(ssum, d, 32);
                    if (k >= 2) r_acc += e / ssum;
                }
            }
        }
        if (wid == 0 && roB2 >= 0 && lane < OUTD) out[roB2 * OUTD + lane] = r_acc;
    } else {
        // ---- compute waves ----
        const float* clp = curL2 + r2 * 36 + half * 16;
        for (int t = 0; t < T_STEPS; ++t) {
            f32x4 a00 = {0,0,0,0}, a01 = {0,0,0,0}, a10 = {0,0,0,0}, a11 = {0,0,0,0};
            #pragma unroll
            for (int k0 = 0; k0 < KPAD; k0 += 32) {
                int k8 = (k0 >> 3) + (lane >> 4);
                short8 f0 = *(const short8*)&Apre2[(((rb2)      * 88 + (k8 ^ sw2)) << 4)];
                short8 f1 = *(const short8*)&Apre2[(((rb2 + 16) * 88 + (k8 ^ sw2)) << 4)];
                short8 b0 = *(const short8*)(&Bp[(colA) * 712 + k0 + kb8]);
                short8 b1 = *(const short8*)(&Bp[(16 + colA) * 712 + k0 + kb8]);
                a00 = __builtin_amdgcn_mfma_f32_16x16x32_bf16(f0, b0, a00, 0, 0, 0);
                a01 = __builtin_amdgcn_mfma_f32_16x16x32_bf16(f0, b1, a01, 0, 0, 0);
                a10 = __builtin_amdgcn_mfma_f32_16x16x32_bf16(f1, b0, a10, 0, 0, 0);
                a11 = __builtin_amdgcn_mfma_f32_16x16x32_bf16(f1, b1, a11, 0, 0, 0);
            }
            asm volatile("s_waitcnt lgkmcnt(0)" ::: "memory");
            __builtin_amdgcn_sched_barrier(0);
            if (t + 1 < T_STEPS) {
                const char* gsrc = (const char*)Xh
                    + (((size_t)(t + 1) * 2 + bhalf) * UPB) * 16 + (size_t)mwid * 45056;
                #pragma unroll
                for (int i = 0; i < 44; ++i)
                    dma16(gsrc + i * 1024 + lane * 16, dst2 + i * 1024);
            }
            {
                const int crow0 = trRow + ((lane >> 4) << 2);
                #pragma unroll
                for (int j = 0; j < 4; ++j) {
                    curL2[(crow0 + j) * 36 + colA]           = a00[j];
                    curL2[(crow0 + j) * 36 + 16 + colA]      = a01[j];
                    curL2[(crow0 + 16 + j) * 36 + colA]      = a10[j];
                    curL2[(crow0 + 16 + j) * 36 + 16 + colA] = a11[j];
                }
            }
            asm volatile("s_waitcnt lgkmcnt(0)" ::: "memory");
            __builtin_amdgcn_sched_barrier(0);

            f32x4 cv0 = *(const f32x4*)(clp + 0);
            f32x4 cv1 = *(const f32x4*)(clp + 4);
            f32x4 cv2 = *(const f32x4*)(clp + 8);
            f32x4 cv3 = *(const f32x4*)(clp + 12);
            float cl[16];
            #pragma unroll
            for (int e = 0; e < 4; ++e) {
                cl[e] = cv0[e]; cl[4 + e] = cv1[e]; cl[8 + e] = cv2[e]; cl[12 + e] = cv3[e];
            }
            float memS[4], spkS[4];
            #pragma unroll
            for (int n = 0; n < 4; ++n) {
                float lin = 0.f;
                #pragma unroll
                for (int j = 0; j < 4; ++j) {
                    int idx = n * 4 + j;
                    dn2[idx] = bt2[idx] * dn2[idx] + omb2[idx] * (cl[idx] + bias2[idx]);
                    lin += dn2[idx];
                }
                memS[n] = alph2[n] * mem2[n] + oma2[n] * lin - spk2[n];
                spkS[n] = (memS[n] > 1.0f) ? 1.0f : 0.0f;
            }
            unsigned nib = 0;
            #pragma unroll
            for (int n = 0; n < 4; ++n) nib |= (spkS[n] != 0.f ? 1u : 0u) << (half * 4 + n);
            nib |= (unsigned)__shfl_xor((int)nib, 1);
            if (half == 0) ((uint8_t*)stageW)[r2] = (uint8_t)nib;
            if (lane == 0) ldsSt(&fStgw[mwid], (unsigned)(t + 1));

            bool anySpk = false;
            if (t > 0) {
                unsigned p0, p1;
                do { p0 = ldsLd(&fPollDone[0]); } while ((p0 >> 1) < (unsigned)t);
                do { p1 = ldsLd(&fPollDone[1]); } while ((p1 >> 1) < (unsigned)t);
                anySpk = ((p0 | p1) & 1u) != 0u;
            }
            if (anySpk) {
                float recv[16];
                #pragma unroll
                for (int e = 0; e < 16; ++e) recv[e] = 0.f;
                const float* Wb = Wst + c0 + half * 16;
                const uint64_t* mrow = (const uint64_t*)(mTb + r2 * 136);
                for (int q = 0; q < 16; ++q) {
                    uint64_t mword = mrow[q];
                    while (mword) {
                        int h = (q << 6) + __builtin_ctzll(mword);
                        mword &= mword - 1;
                        const f32x4* wv = (const f32x4*)(Wb + (long)h * NCOL);
                        f32x4 w0 = wv[0], w1 = wv[1], w2v = wv[2], w3 = wv[3];
                        #pragma unroll
                        for (int e = 0; e < 4; ++e) {
                            recv[e] += w0[e]; recv[4 + e] += w1[e];
                            recv[8 + e] += w2v[e]; recv[12 + e] += w3[e];
                        }
                    }
                }
                #pragma unroll
                for (int n = 0; n < 4; ++n) {
                    float cs = 0.f;
                    #pragma unroll
                    for (int j = 0; j < 4; ++j) {
                        int idx = n * 4 + j;
                        float ad = omb2[idx] * recv[idx];
                        dn2[idx] += ad; cs += ad;
                    }
                    memS[n] += oma2[n] * cs;
                    spkS[n] = (memS[n] > 1.0f) ? 1.0f : 0.0f;
                }
                unsigned nib2 = 0;
                #pragma unroll
                for (int n = 0; n < 4; ++n) nib2 |= (spkS[n] != 0.f ? 1u : 0u) << (half * 4 + n);
                nib2 |= (unsigned)__shfl_xor((int)nib2, 1);
                if (half == 0) ((uint8_t*)stageW)[r2] = (uint8_t)nib2;
                if (roB2 >= 0) while (ldsLd(&fRoSnap) < (unsigned)t) {}
                uint64_t* mz = (uint64_t*)(mTb + r2 * 136) + half * 8;
                #pragma unroll
                for (int e = 0; e < 8; ++e) mz[e] = 0;
                if (lane == 0) ldsSt(&fCorr[mwid], (unsigned)(t + 1));
            }
            #pragma unroll
            for (int n = 0; n < 4; ++n) { mem2[n] = memS[n]; spk2[n] = spkS[n]; }

            if (mwid == 0) {
                while (ldsLd(&fStgw[1]) < (unsigned)(t + 1)) {}
                if (anySpk) while (ldsLd(&fCorr[1]) < (unsigned)(t + 1)) {}
                unsigned pay = (lane < 16) ? stageW[lane] : 0u;
                const size_t pbase = ((size_t)(t & 1) * 2 + bhalf) * 128 + w2;
                if (lane < 16 && pay)
                    __hip_atomic_store(chunks + pbase * 16 + lane,
                                       ((uint64_t)(unsigned)(t + 2) << 32) | (uint64_t)pay,
                                       __ATOMIC_RELAXED, AGENT);
                uint64_t bal = __ballot(pay != 0u);
                if (lane == 0)
                    __hip_atomic_store(sums + pbase,
                                       ((uint64_t)(unsigned)(t + 2) << 32) | (uint64_t)(bal & 0xFFFFull),
                                       __ATOMIC_RELAXED, AGENT);
            }
            asm volatile("s_waitcnt vmcnt(0)" ::: "memory");
        }
    }
}

extern "C" void kernel_launch(void* const* d_in, const int* in_sizes, int n_in,
                              void* d_out, int out_size, void* d_ws, size_t ws_size,
                              hipStream_t stream) {
    (void)in_sizes; (void)n_in; (void)out_size; (void)ws_size;
    const float* x     = (const float*)d_in[0];
    const float* W     = (const float*)d_in[1];
    const float* bv    = (const float*)d_in[2];
    const float* tau_m = (const float*)d_in[3];
    const float* tau_n = (const float*)d_in[4];
    const float* Wr    = (const float*)d_in[5];
    const float* br    = (const float*)d_in[6];
    const float* tau_r = (const float*)d_in[7];
    const float* mem0  = (const float*)d_in[8];

    char* ws = (char*)d_ws;
    uint64_t*        p1flag = (uint64_t*)(ws + O_P1F);
    uint64_t*        sums   = (uint64_t*)(ws + O_SUM);
    uint64_t*        chunks = (uint64_t*)(ws + O_CHK);
    float*           Wst    = (float*)(ws + O_WST);
    __hip_bfloat16*  Wxh    = (__hip_bfloat16*)(ws + O_WXH);
    __hip_bfloat16*  Xh     = (__hip_bfloat16*)(ws + O_XH);

    prep_all<<<8192, 256, 0, stream>>>(x, W, Xh, Wxh, Wst, p1flag, sums, chunks);
    p1_scan<<<512, WGT, 0, stream>>>(Xh, Wxh, bv, tau_m, tau_n, mem0, p1flag);
    p2_fallback<<<256, WGT, 0, stream>>>(Xh, Wxh, Wst, p1flag, sums, chunks,
                                         bv, tau_m, tau_n, Wr, br, tau_r, mem0, (float*)d_out);
}

// Round 15
// 374.819 us; speedup vs baseline: 1.4961x; 1.0272x over previous
//
#include <hip/hip_runtime.h>
#include <hip/hip_bf16.h>
#include <stdint.h>

// DH-SNN forward: two-phase optimistic execution, v6 — A direct global->VGPR.
// Xh layout: [t][rgroup(16 rows)][chunk c(0..21)][q(0..3)][row(0..15)] x 16B. A chunk-load for a
//   wave is base + c*1024 + lane*16 -> ONE coalesced 1KB transaction; LDS image (p2) is
//   naturally bank-conflict-free (rows interleaved at 16B) -> all XOR swizzles deleted.
// p1_scan (512 WGs, 2/CU): zero-spike free-run, WG = 16 rows (rtile=wg&7==XCD) x 64 cols.
//   - A double-buffered in REGISTERS (2x11 frags), loaded global->VGPR; prefetch stays in
//     flight ACROSS the step barrier (only lgkmcnt drained) — no LDS for A at all.
//   - LDS = 16KB parity exchange only; B = 22 frags = 88 VGPR; update(t-1) pipelined into
//     MFMA(t) block; one barrier/step. Violation via memmax; flag per WG.
// p2_fallback: verdict + hoisted readout; rare dirty half runs R7 synchronous algorithm
//   (staging/addressing ported to the new layout).

typedef short short8 __attribute__((ext_vector_type(8)));
typedef float f32x4 __attribute__((ext_vector_type(4)));

#define T_STEPS 250
#define BATCH   128
#define HID     1024
#define NCOL    4096
#define IND     700
#define ISZ     1724
#define KPAD    704
#define OUTD    20
#define WGT     256
#define TSTRIDE 180224    // bytes per t in Xh = 8 rgroups * 22528
#define RGB     22528     // bytes per (t, rgroup)

// ws layout (bytes)
#define O_P1F   0                // u64[512] phase-1 flags
#define O_SUM   4096             // u64[2 parity][2 half][128 wg]
#define O_CHK   8192             // u64[2][2][128][16]
#define O_WST   73728            // f32 [1024][4096]
#define O_WXH   16850944         // bf16 [4096][704]
#define O_XH    22618112         // bf16 [250][8][22][4][16][8] = 45056000 B

// p2 smem arena
#define SM_BP    0
#define SM_A2    45568
#define SM_CURL2 135680
#define SM_MTB   144896
#define SM_TOTAL 153600

#define AGENT __HIP_MEMORY_SCOPE_AGENT

__device__ __forceinline__ float sigmoidf(float x) { return 1.0f / (1.0f + expf(-x)); }

__device__ __forceinline__ unsigned ldsLd(const unsigned* p) {
    return __hip_atomic_load(p, __ATOMIC_ACQUIRE, __HIP_MEMORY_SCOPE_WORKGROUP);
}
__device__ __forceinline__ void ldsSt(unsigned* p, unsigned v) {
    __hip_atomic_store(p, v, __ATOMIC_RELEASE, __HIP_MEMORY_SCOPE_WORKGROUP);
}

__device__ __forceinline__ void dma16(const void* g, void* l) {
    __builtin_amdgcn_global_load_lds(
        (const __attribute__((address_space(1))) unsigned int*)g,
        (__attribute__((address_space(3))) unsigned int*)l, 16, 0, 0);
}

// quad-lane sum (lanes xor 1, xor 2) via DPP quad_perm — pure VALU
__device__ __forceinline__ float qsum4(float v) {
    union { float f; int i; } a, b;
    a.f = v; b.i = __builtin_amdgcn_mov_dpp(a.i, 0xB1, 0xF, 0xF, true); v += b.f;  // xor 1
    a.f = v; b.i = __builtin_amdgcn_mov_dpp(a.i, 0x4E, 0xF, 0xF, true); v += b.f;  // xor 2
    return v;
}

__device__ __forceinline__ short bf16bits(float v) {
    union { __hip_bfloat16 h; short s; } u;
    u.h = __float2bfloat16(v);
    return u.s;
}

// ================= fused prep: x re-layout | W->bf16 + zero flags | W^T =================
__global__ __launch_bounds__(256) void prep_all(
    const float* __restrict__ x, const float* __restrict__ W,
    __hip_bfloat16* __restrict__ Xh, __hip_bfloat16* __restrict__ Wxh,
    float* __restrict__ Wst, uint64_t* __restrict__ p1f,
    uint64_t* __restrict__ sums, uint64_t* __restrict__ chunks)
{
    const int bid = blockIdx.x;
    const int tid = threadIdx.x;

    if (bid < 2048) {
        // x -> Xh: unit u = ((t*8+rg)*1408) + c*64 + q*16 + rl
        // holds bf16 x[b=rg*16+rl][t][k=(c*4+q)*8 + e], zero-padded k>=700.
        const int total = T_STEPS * 8 * 1408;
        for (int u = bid * 256 + tid; u < total; u += 2048 * 256) {
            int t   = u / 11264;
            int rem = u % 11264;
            int rg  = rem / 1408;
            int v   = rem % 1408;
            int c   = v >> 6;
            int w   = v & 63;
            int q   = w >> 4, rl = w & 15;
            int b   = rg * 16 + rl;
            int k0  = (c * 4 + q) * 8;
            const float* xp = x + ((long)b * T_STEPS + t) * IND + k0;
            short8 o;
            if (k0 + 8 <= IND) {
                f32x4 v0 = *(const f32x4*)xp;
                f32x4 v1 = *(const f32x4*)(xp + 4);
                #pragma unroll
                for (int e = 0; e < 4; ++e) { o[e] = bf16bits(v0[e]); o[4 + e] = bf16bits(v1[e]); }
            } else {
                #pragma unroll
                for (int e = 0; e < 8; ++e)
                    o[e] = bf16bits((k0 + e < IND) ? xp[e] : 0.0f);
            }
            *(short8*)(Xh + (size_t)u * 8) = o;
        }
    } else if (bid < 4096) {
        if (bid == 2048) {   // zero exchange area every launch (graph replay + 0xAA poison)
            for (int i = tid; i < 512; i += 256)
                __hip_atomic_store(&p1f[i], 0ull, __ATOMIC_RELAXED, AGENT);
            for (int i = tid; i < 2 * 2 * 128; i += 256)
                __hip_atomic_store(&sums[i], 0ull, __ATOMIC_RELAXED, AGENT);
            for (int i = tid; i < 2 * 2 * 128 * 16; i += 256)
                __hip_atomic_store(&chunks[i], 0ull, __ATOMIC_RELAXED, AGENT);
        }
        const int total = NCOL * 88;
        for (int unit = (bid - 2048) * 256 + tid; unit < total; unit += 2048 * 256) {
            int n = unit / 88, m = unit % 88;
            int k0 = m * 8;
            const float* wp = W + (long)n * ISZ + k0;
            short8 o;
            if (k0 + 8 <= IND) {
                f32x4 v0 = *(const f32x4*)wp;
                f32x4 v1 = *(const f32x4*)(wp + 4);
                #pragma unroll
                for (int e = 0; e < 4; ++e) { o[e] = bf16bits(v0[e]); o[4 + e] = bf16bits(v1[e]); }
            } else {
                #pragma unroll
                for (int e = 0; e < 8; ++e)
                    o[e] = bf16bits((k0 + e < IND) ? wp[e] : 0.0f);
            }
            *(short8*)(Wxh + (long)n * KPAD + k0) = o;
        }
    } else {
        // Wst[h][n] = W[n][700+h]
        __shared__ float tile[32][33];
        const int idx = bid - 4096;
        const int h0 = (idx & 31) * 32, n0 = (idx >> 5) * 32;
        const int tx = tid & 31, ty = tid >> 5;
        #pragma unroll
        for (int j = 0; j < 32; j += 8)
            tile[ty + j][tx] = W[(long)(n0 + ty + j) * ISZ + IND + h0 + tx];
        __syncthreads();
        #pragma unroll
        for (int j = 0; j < 32; j += 8)
            Wst[(long)(h0 + ty + j) * NCOL + n0 + tx] = tile[tx][ty + j];
    }
}

// ======================= p1: A-in-registers free-run (512 WGs, 2/CU) =======================
__global__ __launch_bounds__(256, 2) void p1_scan(
    const __hip_bfloat16* __restrict__ Xh, const __hip_bfloat16* __restrict__ Wxh,
    const float* __restrict__ bvec, const float* __restrict__ tau_m,
    const float* __restrict__ tau_n, const float* __restrict__ mem0,
    uint64_t* __restrict__ p1f)
{
    __shared__ __align__(16) float preg[2][8 * 256];    // 16384 B parity exchange
    __shared__ unsigned anySpkF;

    const int wg    = blockIdx.x;        // 0..511
    const int rtile = wg & 7;            // batch rows [rtile*16,+16)  (== XCD round-robin)
    const int ctile = wg >> 3;           // cols [ctile*64,+64)
    const int tid   = threadIdx.x;
    const int lane  = tid & 63, wid = tid >> 6;
    const int colA  = lane & 15, kb8 = (lane >> 4) * 8;
    const int cg    = wid >> 1;          // col half
    const int p     = wid & 1;           // k half: chunks [11p, 11p+11)

    if (tid == 0) anySpkF = 0u;

    // per-lane state (MFMA C-layout): 2 cols x 4 rows
    const int colG0 = ctile * 64 + cg * 32 + colA;
    const int colG1 = colG0 + 16;
    const int rowB  = rtile * 16 + (lane >> 4) * 4;
    float bt_[2], omb_[2], bias_[2], al_[2], oma_[2], dn[2][4], mem_[2][4];
    {
        const int cG[2] = {colG0, colG1};
        #pragma unroll
        for (int i = 0; i < 2; ++i) {
            bt_[i]   = sigmoidf(tau_n[cG[i]]);
            omb_[i]  = 1.0f - bt_[i];
            bias_[i] = bvec[cG[i]];
            al_[i]   = sigmoidf(tau_m[cG[i] >> 2]);
            oma_[i]  = 1.0f - al_[i];
            #pragma unroll
            for (int j = 0; j < 4; ++j) {
                dn[i][j]   = 0.0f;
                mem_[i][j] = mem0[(rowB + j) * HID + (cG[i] >> 2)];
            }
        }
    }

    // B panel -> registers: 22 frags = 88 VGPR
    short8 Breg[22];
    #pragma unroll
    for (int j = 0; j < 11; ++j) {
        Breg[2 * j]     = *(const short8*)(Wxh + (long)colG0 * KPAD + (11 * p + j) * 32 + kb8);
        Breg[2 * j + 1] = *(const short8*)(Wxh + (long)colG1 * KPAD + (11 * p + j) * 32 + kb8);
    }
    asm volatile("s_waitcnt vmcnt(0)" ::: "memory");
    __builtin_amdgcn_sched_barrier(0);
    #pragma unroll
    for (int i = 0; i < 22; ++i) asm volatile("" : "+v"(Breg[i]));

    // A load base: per step t, chunk c: Xh + t*TSTRIDE + rtile*RGB + c*1024 + lane*16
    const char* Abase = (const char*)Xh + (size_t)rtile * RGB + (size_t)(11 * p) * 1024
                        + (size_t)lane * 16;

    #define LOADA(T, A)                                                        \
        do {                                                                   \
            const char* _g = Abase + (size_t)(T) * TSTRIDE;                    \
            _Pragma("unroll")                                                  \
            for (int _j = 0; _j < 11; ++_j)                                    \
                (A)[_j] = *(const short8*)(_g + _j * 1024);                    \
        } while (0)

    #define MFMA_R(A, a0, a1)                                                                  \
        do {                                                                                   \
            _Pragma("unroll")                                                                  \
            for (int _j = 0; _j < 11; ++_j) {                                                  \
                a0 = __builtin_amdgcn_mfma_f32_16x16x32_bf16((A)[_j], Breg[2 * _j],     a0, 0,0,0); \
                a1 = __builtin_amdgcn_mfma_f32_16x16x32_bf16((A)[_j], Breg[2 * _j + 1], a1, 0,0,0); \
            }                                                                                  \
        } while (0)

    #define UPDATE_STEP(CS0, CS1)                                                  \
        do {                                                                       \
            _Pragma("unroll")                                                      \
            for (int _j = 0; _j < 4; ++_j) {                                       \
                float _d0 = bt_[0] * dn[0][_j] + omb_[0] * ((CS0)[_j] + bias_[0]); \
                float _d1 = bt_[1] * dn[1][_j] + omb_[1] * ((CS1)[_j] + bias_[1]); \
                dn[0][_j] = _d0; dn[1][_j] = _d1;                                  \
                float _l0 = qsum4(_d0), _l1 = qsum4(_d1);                          \
                float _m0 = al_[0] * mem_[0][_j] + oma_[0] * _l0;                  \
                float _m1 = al_[1] * mem_[1][_j] + oma_[1] * _l1;                  \
                mem_[0][_j] = _m0; mem_[1][_j] = _m1;                              \
                memmax = fmaxf(memmax, fmaxf(_m0, _m1));                           \
            }                                                                      \
        } while (0)

    // one step: (optional load of next A-buffer) | MFMA | pipelined update(s-1) | exchange
    #define HALF(S, ACUR, ANEXT, DO_LOAD, DO_UPD)                              \
        do {                                                                   \
            if (DO_LOAD) { LOADA((S) + 1, ANEXT); }                            \
            __builtin_amdgcn_sched_barrier(0);                                 \
            f32x4 _a0 = {0,0,0,0}, _a1 = {0,0,0,0};                            \
            MFMA_R(ACUR, _a0, _a1);                                            \
            if (DO_UPD) {                                                      \
                f32x4 _cs0 = own0 + prt0;                                      \
                f32x4 _cs1 = own1 + prt1;                                      \
                UPDATE_STEP(_cs0, _cs1);                                       \
            }                                                                  \
            float* _wq = &preg[(S) & 1][wrSlot * 256 + lane * 4];              \
            *(f32x4*)_wq = _a0; *(f32x4*)(_wq + 256) = _a1;                    \
            asm volatile("s_waitcnt lgkmcnt(0)" ::: "memory");                 \
            __builtin_amdgcn_sched_barrier(0);                                 \
            __builtin_amdgcn_s_barrier();                                      \
            const float* _rq = &preg[(S) & 1][rdSlot * 256 + lane * 4];        \
            prt0 = *(const f32x4*)_rq; prt1 = *(const f32x4*)(_rq + 256);      \
            own0 = _a0; own1 = _a1;                                            \
        } while (0)

    float memmax = -1e30f;
    f32x4 own0, own1, prt0, prt1;
    const int wrSlot = (cg * 2 + (1 - p)) * 2;
    const int rdSlot = (cg * 2 + p) * 2;

    short8 A0[11], A1[11];
    LOADA(0, A0);
    __syncthreads();                       // preg zero-init not needed; just wave alignment

    HALF(0, A0, A1, true, false);          // s=0: prefetch A1<-1, no update
    for (int t = 1; t < 249; t += 2) {
        HALF(t,     A1, A0, true, true);   // prefetch A0 <- t+1
        HALF(t + 1, A0, A1, true, true);   // prefetch A1 <- t+2 (max 249)
    }
    HALF(249, A1, A0, false, true);
    {   // epilogue: update for s = 249
        f32x4 cs0 = own0 + prt0;
        f32x4 cs1 = own1 + prt1;
        UPDATE_STEP(cs0, cs1);
    }

    if (__any(memmax > 1.0f) && lane == 0) anySpkF = 1u;
    __syncthreads();
    if (tid == 0)
        __hip_atomic_store(p1f + wg, (1ull << 32) | (uint64_t)anySpkF,
                           __ATOMIC_RELAXED, AGENT);
    #undef LOADA
    #undef MFMA_R
    #undef UPDATE_STEP
    #undef HALF
}

// ============== p2: verdict + hoisted readout + rare synchronous fallback (R7) ==============
__global__ __launch_bounds__(256, 1) void p2_fallback(
    const __hip_bfloat16* __restrict__ Xh, const __hip_bfloat16* __restrict__ Wxh,
    const float* __restrict__ Wst, const uint64_t* __restrict__ p1f,
    uint64_t* __restrict__ sums, uint64_t* __restrict__ chunks,
    const float* __restrict__ bvec, const float* __restrict__ tau_m, const float* __restrict__ tau_n,
    const float* __restrict__ Wr, const float* __restrict__ brv, const float* __restrict__ tau_r,
    const float* __restrict__ mem0, float* __restrict__ out)
{
    __shared__ __align__(16) char smem[SM_TOTAL];
    __shared__ uint32_t stageW[16];
    __shared__ uint64_t roSnap[16];
    __shared__ unsigned fPollDone[2], fStgw[2], fCorr[2];
    __shared__ unsigned fRoSnap, dirtyH[2];

    __hip_bfloat16* Bp    = (__hip_bfloat16*)(smem + SM_BP);
    uint8_t*        Apre2 = (uint8_t*)(smem + SM_A2);
    float*          curL2 = (float*)(smem + SM_CURL2);
    uint8_t*        mTb   = (uint8_t*)(smem + SM_MTB);

    const int wg   = blockIdx.x;     // 0..255
    const int tid  = threadIdx.x;
    const int lane = tid & 63, wid = tid >> 6;
    const int colA = lane & 15, kb8 = (lane >> 4) * 8;

    if (tid < 2) { fPollDone[tid] = 0; fStgw[tid] = 0; fCorr[tid] = 0; dirtyH[tid] = 0; }
    if (tid == 0) fRoSnap = 0;
    __syncthreads();

    // verdict from p1 flags (stream-ordered: plain loads)
    {
        uint64_t v0 = p1f[tid];
        uint64_t v1 = p1f[tid + 256];
        if ((unsigned)v0) dirtyH[(tid & 7) >> 2] = 1u;
        if ((unsigned)v1) dirtyH[((tid + 256) & 7) >> 2] = 1u;
    }
    __syncthreads();

    float r_alpha = 0.f, r_bias = 0.f;
    const float* WrRow = Wr;
    if (wid == 0 && lane < 32) {
        int o = (lane < OUTD) ? lane : 0;
        r_alpha = sigmoidf(tau_r[o]);
        r_bias  = brv[o];
        WrRow   = Wr + o * HID;
    }

    // clean halves: hoisted readout (input-independent under zero spikes), b = wg
    if (wg < BATCH && wid == 0 && lane < 32 && !dirtyH[wg >> 6]) {
        float rr = 0.f, racc = 0.f;
        for (int t = 0; t < T_STEPS; ++t) {
            rr = r_alpha * rr + (1.0f - r_alpha) * r_bias;
            float vmax = (lane < OUTD) ? rr : -__builtin_inff();
            #pragma unroll
            for (int d = 16; d > 0; d >>= 1) vmax = fmaxf(vmax, __shfl_xor(vmax, d, 32));
            float e = (lane < OUTD) ? expf(rr - vmax) : 0.f;
            float ss = e;
            #pragma unroll
            for (int d = 16; d > 0; d >>= 1) ss += __shfl_xor(ss, d, 32);
            if (t >= 1) racc += e / ss;
        }
        if (lane < OUTD) out[wg * OUTD + lane] = racc;
    }
    if (!dirtyH[wg >> 7]) return;

    // ---------------- synchronous fallback (R7, tags +1; new Xh layout) ----------------
    float r_rmem = 0.f, r_acc = 0.f;
    const int w2    = wg & 127;
    const int bhalf = wg >> 7;
    const int bbase = bhalf * 64;
    const int c0    = w2 * 32;
    const int i0    = w2 * 8;
    const int roB2  = (wg < 64) ? wg : ((wg >= 128 && wg < 192) ? wg - 64 : -1);

    for (int idx = tid; idx < 32 * 88; idx += WGT) {
        int col = idx / 88, m = idx % 88;
        *(short8*)(Bp + col * 712 + m * 8) = *(const short8*)(Wxh + (long)(c0 + col) * KPAD + m * 8);
    }
    for (int idx = tid; idx < 64 * 136 / 4; idx += WGT)
        ((uint32_t*)mTb)[idx] = 0u;

    const int mwid = wid - 2;
    const int st   = tid - 128;
    const int r2   = st >> 1;
    const int half = st & 1;
    float dn2[16], bt2[16], omb2[16], bias2[16], alph2[4], oma2[4], mem2[4], spk2[4];
    if (wid >= 2) {
        const int b2 = bbase + r2;
        #pragma unroll
        for (int n = 0; n < 4; ++n) {
            int i = i0 + half * 4 + n;
            alph2[n] = sigmoidf(tau_m[i]);
            oma2[n]  = 1.0f - alph2[n];
            mem2[n]  = mem0[b2 * HID + i];
            spk2[n]  = 0.0f;
            #pragma unroll
            for (int j = 0; j < 4; ++j) {
                int idx = n * 4 + j;
                bt2[idx]   = sigmoidf(tau_n[i * 4 + j]);
                omb2[idx]  = 1.0f - bt2[idx];
                bias2[idx] = bvec[i * 4 + j];
                dn2[idx]   = 0.0f;
            }
        }
    }
    const int trRow = mwid * 32;
    const int rb2   = trRow + (lane & 15);
    uint8_t* dst2   = Apre2 + mwid * 45056;     // stages rgroups bhalf*4+mwid*2, +1
    const int rg0   = bhalf * 4 + mwid * 2;

    // staging macro for step T: two rgroups, 22 x 1KB units each, linear dst
    #define P2_STAGE(T)                                                               \
        do {                                                                          \
            _Pragma("unroll")                                                         \
            for (int _g = 0; _g < 2; ++_g) {                                          \
                const char* _src = (const char*)Xh + ((size_t)(T) * 8 + rg0 + _g) * RGB; \
                _Pragma("unroll")                                                     \
                for (int _i = 0; _i < 22; ++_i)                                       \
                    dma16(_src + _i * 1024 + (size_t)lane * 16,                       \
                          dst2 + _g * RGB + _i * 1024);                               \
            }                                                                         \
        } while (0)

    if (wid >= 2) P2_STAGE(0);
    asm volatile("s_waitcnt vmcnt(0)" ::: "memory");
    __syncthreads();

    if (wid < 2) {
        // ---- poll waves ----
        const int plane = tid;
        for (int k = 1; k <= T_STEPS; ++k) {
            const size_t base = ((size_t)((k - 1) & 1) * 2 + bhalf) * 128 + plane;
            const unsigned want = (unsigned)(k + 1);
            uint64_t v;
            for (;;) {
                v = __hip_atomic_load(sums + base, __ATOMIC_RELAXED, AGENT);
                if ((unsigned)(v >> 32) == want) break;
                __builtin_amdgcn_s_sleep(1);
            }
            unsigned mysum = (unsigned)v;
            if (mysum) {
                if (wid == 1)
                    while (ldsLd(&fRoSnap) < (unsigned)(k - 1)) {}
                const uint64_t* rec = chunks + base * 16;
                uint8_t* col = mTb + plane;
                unsigned pend = mysum;
                while (pend) {
                    int c = __builtin_ctz(pend);
                    uint64_t cv = __hip_atomic_load(rec + c, __ATOMIC_RELAXED, AGENT);
                    if ((unsigned)(cv >> 32) == want) {
                        pend &= pend - 1;
                        unsigned pay = (unsigned)cv;
                        col[(4 * c + 0) * 136] = (uint8_t)(pay);
                        col[(4 * c + 1) * 136] = (uint8_t)(pay >> 8);
                        col[(4 * c + 2) * 136] = (uint8_t)(pay >> 16);
                        col[(4 * c + 3) * 136] = (uint8_t)(pay >> 24);
                    } else {
                        __builtin_amdgcn_s_sleep(1);
                    }
                }
            }
            const bool anyW = __any(mysum != 0u);
            if (lane == 0)
                ldsSt(&fPollDone[wid], ((unsigned)k << 1) | (anyW ? 1u : 0u));

            if (wid == 0) {
                while ((ldsLd(&fPollDone[1]) >> 1) < (unsigned)k) {}
                if (roB2 >= 0 && lane < 16)
                    roSnap[lane] = ((const uint64_t*)(mTb + (roB2 & 63) * 136))[lane];
                asm volatile("s_waitcnt lgkmcnt(0)" ::: "memory");
                if (lane == 0) ldsSt(&fRoSnap, (unsigned)k);
                if (roB2 >= 0 && lane < 32) {
                    float rsum = 0.f;
                    #pragma unroll 4
                    for (int q = 0; q < 16; ++q) {
                        uint64_t mword = roSnap[q];
                        while (mword) {
                            int h = (q << 6) + __builtin_ctzll(mword);
                            mword &= mword - 1;
                            rsum += WrRow[h];
                        }
                    }
                    r_rmem = r_alpha * r_rmem + (1.0f - r_alpha) * (rsum + r_bias);
                    float vmax = (lane < OUTD) ? r_rmem : -__builtin_inff();
                    #pragma unroll
                    for (int d = 16; d > 0; d >>= 1) vmax = fmaxf(vmax, __shfl_xor(vmax, d, 32));
                    float e = (lane < OUTD) ? expf(r_rmem - vmax) : 0.f;
                    float ssum = e;
                    #pragma unroll
                    for (int d = 16; d > 0; d >>= 1) ssum += __shfl_xor(ssum, d, 32);
                    if (k >= 2) r_acc += e / ssum;
                }
            }
        }
        if (wid == 0 && roB2 >= 0 && lane < OUTD) out[roB2 * OUTD + lane] = r_acc;
    } else {
        // ---- compute waves ----
        const float* clp = curL2 + r2 * 36 + half * 16;
        for (int t = 0; t < T_STEPS; ++t) {
            f32x4 a00 = {0,0,0,0}, a01 = {0,0,0,0}, a10 = {0,0,0,0}, a11 = {0,0,0,0};
            #pragma unroll
            for (int k0 = 0; k0 < KPAD; k0 += 32) {
                // A byte in Apre2 for local row r, k8=(k0>>3)+(lane>>4):
                //   (r>>4)*RGB + (k8>>2)*1024 + (k8&3)*256 + (r&15)*16
                int c  = k0 >> 5;
                int q  = lane >> 4;
                int rl = rb2 & 15;
                const uint8_t* ab = Apre2 + (rb2 >> 4) * RGB + c * 1024 + q * 256 + rl * 16;
                short8 f0 = *(const short8*)(ab);
                short8 f1 = *(const short8*)(ab + RGB);   // row rb2+16 -> next rgroup
                short8 b0 = *(const short8*)(&Bp[(colA) * 712 + k0 + kb8]);
                short8 b1 = *(const short8*)(&Bp[(16 + colA) * 712 + k0 + kb8]);
                a00 = __builtin_amdgcn_mfma_f32_16x16x32_bf16(f0, b0, a00, 0, 0, 0);
                a01 = __builtin_amdgcn_mfma_f32_16x16x32_bf16(f0, b1, a01, 0, 0, 0);
                a10 = __builtin_amdgcn_mfma_f32_16x16x32_bf16(f1, b0, a10, 0, 0, 0);
                a11 = __builtin_amdgcn_mfma_f32_16x16x32_bf16(f1, b1, a11, 0, 0, 0);
            }
            asm volatile("s_waitcnt lgkmcnt(0)" ::: "memory");
            __builtin_amdgcn_sched_barrier(0);
            if (t + 1 < T_STEPS) P2_STAGE(t + 1);
            {
                const int crow0 = trRow + ((lane >> 4) << 2);
                #pragma unroll
                for (int j = 0; j < 4; ++j) {
                    curL2[(crow0 + j) * 36 + colA]           = a00[j];
                    curL2[(crow0 + j) * 36 + 16 + colA]      = a01[j];
                    curL2[(crow0 + 16 + j) * 36 + colA]      = a10[j];
                    curL2[(crow0 + 16 + j) * 36 + 16 + colA] = a11[j];
                }
            }
            asm volatile("s_waitcnt lgkmcnt(0)" ::: "memory");
            __builtin_amdgcn_sched_barrier(0);

            f32x4 cv0 = *(const f32x4*)(clp + 0);
            f32x4 cv1 = *(const f32x4*)(clp + 4);
            f32x4 cv2 = *(const f32x4*)(clp + 8);
            f32x4 cv3 = *(const f32x4*)(clp + 12);
            float cl[16];
            #pragma unroll
            for (int e = 0; e < 4; ++e) {
                cl[e] = cv0[e]; cl[4 + e] = cv1[e]; cl[8 + e] = cv2[e]; cl[12 + e] = cv3[e];
            }
            float memS[4], spkS[4];
            #pragma unroll
            for (int n = 0; n < 4; ++n) {
                float lin = 0.f;
                #pragma unroll
                for (int j = 0; j < 4; ++j) {
                    int idx = n * 4 + j;
                    dn2[idx] = bt2[idx] * dn2[idx] + omb2[idx] * (cl[idx] + bias2[idx]);
                    lin += dn2[idx];
                }
                memS[n] = alph2[n] * mem2[n] + oma2[n] * lin - spk2[n];
                spkS[n] = (memS[n] > 1.0f) ? 1.0f : 0.0f;
            }
            unsigned nib = 0;
            #pragma unroll
            for (int n = 0; n < 4; ++n) nib |= (spkS[n] != 0.f ? 1u : 0u) << (half * 4 + n);
            nib |= (unsigned)__shfl_xor((int)nib, 1);
            if (half == 0) ((uint8_t*)stageW)[r2] = (uint8_t)nib;
            if (lane == 0) ldsSt(&fStgw[mwid], (unsigned)(t + 1));

            bool anySpk = false;
            if (t > 0) {
                unsigned p0, p1v;
                do { p0 = ldsLd(&fPollDone[0]); } while ((p0 >> 1) < (unsigned)t);
                do { p1v = ldsLd(&fPollDone[1]); } while ((p1v >> 1) < (unsigned)t);
                anySpk = ((p0 | p1v) & 1u) != 0u;
            }
            if (anySpk) {
                float recv[16];
                #pragma unroll
                for (int e = 0; e < 16; ++e) recv[e] = 0.f;
                const float* Wb = Wst + c0 + half * 16;
                const uint64_t* mrow = (const uint64_t*)(mTb + r2 * 136);
                for (int q = 0; q < 16; ++q) {
                    uint64_t mword = mrow[q];
                    while (mword) {
                        int h = (q << 6) + __builtin_ctzll(mword);
                        mword &= mword - 1;
                        const f32x4* wv = (const f32x4*)(Wb + (long)h * NCOL);
                        f32x4 w0 = wv[0], w1 = wv[1], w2v = wv[2], w3 = wv[3];
                        #pragma unroll
                        for (int e = 0; e < 4; ++e) {
                            recv[e] += w0[e]; recv[4 + e] += w1[e];
                            recv[8 + e] += w2v[e]; recv[12 + e] += w3[e];
                        }
                    }
                }
                #pragma unroll
                for (int n = 0; n < 4; ++n) {
                    float cs = 0.f;
                    #pragma unroll
                    for (int j = 0; j < 4; ++j) {
                        int idx = n * 4 + j;
                        float ad = omb2[idx] * recv[idx];
                        dn2[idx] += ad; cs += ad;
                    }
                    memS[n] += oma2[n] * cs;
                    spkS[n] = (memS[n] > 1.0f) ? 1.0f : 0.0f;
                }
                unsigned nib2 = 0;
                #pragma unroll
                for (int n = 0; n < 4; ++n) nib2 |= (spkS[n] != 0.f ? 1u : 0u) << (half * 4 + n);
                nib2 |= (unsigned)__shfl_xor((int)nib2, 1);
                if (half == 0) ((uint8_t*)stageW)[r2] = (uint8_t)nib2;
                if (roB2 >= 0) while (ldsLd(&fRoSnap) < (unsigned)t) {}
                uint64_t* mz = (uint64_t*)(mTb + r2 * 136) + half * 8;
                #pragma unroll
                for (int e = 0; e < 8; ++e) mz[e] = 0;
                if (lane == 0) ldsSt(&fCorr[mwid], (unsigned)(t + 1));
            }
            #pragma unroll
            for (int n = 0; n < 4; ++n) { mem2[n] = memS[n]; spk2[n] = spkS[n]; }

            if (mwid == 0) {
                while (ldsLd(&fStgw[1]) < (unsigned)(t + 1)) {}
                if (anySpk) while (ldsLd(&fCorr[1]) < (unsigned)(t + 1)) {}
                unsigned pay = (lane < 16) ? stageW[lane] : 0u;
                const size_t pbase = ((size_t)(t & 1) * 2 + bhalf) * 128 + w2;
                if (lane < 16 && pay)
                    __hip_atomic_store(chunks + pbase * 16 + lane,
                                       ((uint64_t)(unsigned)(t + 2) << 32) | (uint64_t)pay,
                                       __ATOMIC_RELAXED, AGENT);
                uint64_t bal = __ballot(pay != 0u);
                if (lane == 0)
                    __hip_atomic_store(sums + pbase,
                                       ((uint64_t)(unsigned)(t + 2) << 32) | (uint64_t)(bal & 0xFFFFull),
                                       __ATOMIC_RELAXED, AGENT);
            }
            asm volatile("s_waitcnt vmcnt(0)" ::: "memory");
        }
    }
    #undef P2_STAGE
}

extern "C" void kernel_launch(void* const* d_in, const int* in_sizes, int n_in,
                              void* d_out, int out_size, void* d_ws, size_t ws_size,
                              hipStream_t stream) {
    (void)in_sizes; (void)n_in; (void)out_size; (void)ws_size;
    const float* x     = (const float*)d_in[0];
    const float* W     = (const float*)d_in[1];
    const float* bv    = (const float*)d_in[2];
    const float* tau_m = (const float*)d_in[3];
    const float* tau_n = (const float*)d_in[4];
    const float* Wr    = (const float*)d_in[5];
    const float* br    = (const float*)d_in[6];
    const float* tau_r = (const float*)d_in[7];
    const float* mem0  = (const float*)d_in[8];

    char* ws = (char*)d_ws;
    uint64_t*        p1flag = (uint64_t*)(ws + O_P1F);
    uint64_t*        sums   = (uint64_t*)(ws + O_SUM);
    uint64_t*        chunks = (uint64_t*)(ws + O_CHK);
    float*           Wst    = (float*)(ws + O_WST);
    __hip_bfloat16*  Wxh    = (__hip_bfloat16*)(ws + O_WXH);
    __hip_bfloat16*  Xh     = (__hip_bfloat16*)(ws + O_XH);

    prep_all<<<8192, 256, 0, stream>>>(x, W, Xh, Wxh, Wst, p1flag, sums, chunks);
    p1_scan<<<512, WGT, 0, stream>>>(Xh, Wxh, bv, tau_m, tau_n, mem0, p1flag);
    p2_fallback<<<256, WGT, 0, stream>>>(Xh, Wxh, Wst, p1flag, sums, chunks,
                                         bv, tau_m, tau_n, Wr, br, tau_r, mem0, (float*)d_out);
}